// Round 1
// 1204.546 us; speedup vs baseline: 1.7290x; 1.7290x over previous
//
#include <hip/hip_runtime.h>

typedef unsigned short u16;
typedef __attribute__((ext_vector_type(8))) short short8;
typedef __attribute__((ext_vector_type(4))) float f32x4;

#define NROW 8192

__device__ __forceinline__ float bf2f(u16 h) {
  unsigned u = ((unsigned)h) << 16;
  return __builtin_bit_cast(float, u);
}
// mode-aware load: f32 ? fp32 storage : bf16 storage (upcast)
__device__ __forceinline__ float ldf(const void* p, size_t i, int f32) {
  return f32 ? ((const float*)p)[i] : bf2f(((const u16*)p)[i]);
}
// fp32 -> bf16 round-to-nearest-even
__device__ __forceinline__ u16 f2bf(float f) {
  unsigned b = __builtin_bit_cast(unsigned, f);
  b += 0x7FFFu + ((b >> 16) & 1u);
  return (u16)(b >> 16);
}
// order-preserving float->uint key for atomicMax
__device__ __forceinline__ unsigned fkey(float f) {
  unsigned b = __builtin_bit_cast(unsigned, f);
  return (b & 0x80000000u) ? ~b : (b | 0x80000000u);
}
__device__ __forceinline__ float fkeydec(unsigned k) {
  unsigned b = (k & 0x80000000u) ? (k & 0x7FFFFFFFu) : ~k;
  return __builtin_bit_cast(float, b);
}

// ---- storage-dtype detection on x (N(0,1)).
__global__ void detect3(const u16* __restrict__ xr, unsigned* __restrict__ mode) {
  __shared__ int zc, bg;
  int t = threadIdx.x;   // 256
  if (t == 0) { zc = 0; bg = 0; }
  __syncthreads();
  int zeros_even = 0; int big = 0;
  for (int i = t; i < 4096; i += 256) {
    u16 v = xr[i];
    if (!(i & 1) && v == 0) zeros_even++;
    if (fabsf(bf2f(v)) > 1e6f) big = 1;
  }
  atomicAdd(&zc, zeros_even);
  if (big) atomicOr(&bg, 1);
  __syncthreads();
  if (t == 0) *mode = (zc > 512 || bg) ? 1u : 0u;   // 1 = fp32 storage
}

// ---- adj storage detection (u32 pair pattern 0x00003F80 unique to bf16).
__global__ void detect_adj(const unsigned* __restrict__ a, unsigned* __restrict__ amode) {
  __shared__ int clo;
  int t = threadIdx.x;   // 256
  if (t == 0) clo = 0;
  __syncthreads();
  int c = 0;
  for (int i = t; i < 4096; i += 256)
    if (a[i] == 0x00003F80u) c++;
  atomicAdd(&clo, c);
  __syncthreads();
  if (t == 0) *amode = (clo > 32) ? 1u : 0u;   // 1 = bf16 storage
}

// 8 adjacency bits at element offset base (base % 8 == 0).
__device__ __forceinline__ void mask8(const void* adj, size_t base, int amode, int* aa) {
  if (amode == 0) {   // int32 or fp32 storage: one u32 per element, !=0 test
    int4 a0 = *(const int4*)((const int*)adj + base);
    int4 a1 = *(const int4*)((const int*)adj + base + 4);
    aa[0] = a0.x != 0; aa[1] = a0.y != 0; aa[2] = a0.z != 0; aa[3] = a0.w != 0;
    aa[4] = a1.x != 0; aa[5] = a1.y != 0; aa[6] = a1.z != 0; aa[7] = a1.w != 0;
  } else {            // bf16 storage: one u16 per element
    ushort4 a0 = *(const ushort4*)((const u16*)adj + base);
    ushort4 a1 = *(const ushort4*)((const u16*)adj + base + 4);
    aa[0] = a0.x != 0; aa[1] = a0.y != 0; aa[2] = a0.z != 0; aa[3] = a0.w != 0;
    aa[4] = a1.x != 0; aa[5] = a1.y != 0; aa[6] = a1.z != 0; aa[7] = a1.w != 0;
  }
}

// C[M x N] fp32 = A[M x K] @ B[K x N]; A/B raw (mode-aware) or fp32 ws buffers.
__global__ __launch_bounds__(256) void gemm_f32(const void* __restrict__ A,
    const void* __restrict__ B, float* __restrict__ C, int K, int N,
    const unsigned* __restrict__ modep, int araw, int braw) {
  int f32a = araw ? (int)*modep : 1;
  int f32b = braw ? (int)*modep : 1;
  __shared__ float sA[16][68];
  __shared__ float sB[16][68];
  int tid = threadIdx.x;
  int rb = blockIdx.y, cb = blockIdx.x;
  int tx = tid & 15, ty = tid >> 4;
  float acc[4][4] = {};
  for (int kt = 0; kt < K; kt += 16) {
    __syncthreads();
#pragma unroll
    for (int it = 0; it < 4; ++it) {
      int idx = tid + it * 256;          // 0..1023
      int m = idx & 63, kk = idx >> 6;
      sA[kk][m] = ldf(A, (size_t)(rb * 64 + m) * K + kt + kk, f32a);
      sB[kk][m] = ldf(B, (size_t)(kt + kk) * N + cb * 64 + m, f32b);
    }
    __syncthreads();
#pragma unroll
    for (int k = 0; k < 16; ++k) {
      float4 av = *(const float4*)&sA[k][ty * 4];
      float4 bv = *(const float4*)&sB[k][tx * 4];
      float aa[4] = {av.x, av.y, av.z, av.w};
      float bb[4] = {bv.x, bv.y, bv.z, bv.w};
#pragma unroll
      for (int r = 0; r < 4; ++r)
#pragma unroll
        for (int c = 0; c < 4; ++c) acc[r][c] += aa[r] * bb[c];
    }
  }
#pragma unroll
  for (int r = 0; r < 4; ++r)
#pragma unroll
    for (int c = 0; c < 4; ++c)
      C[(size_t)(rb * 64 + ty * 4 + r) * N + cb * 64 + tx * 4 + c] = acc[r][c];
}

// transpose + bf16 convert: in fp32 [M][F] -> out bf16 [F][M]. grid (M/32, F/32).
__global__ __launch_bounds__(256) void transpose_bf16(const float* __restrict__ in,
    u16* __restrict__ out, int M, int F) {
  __shared__ float t[32][33];
  int m0 = blockIdx.x * 32, f0 = blockIdx.y * 32;
  int c = threadIdx.x & 31, r = threadIdx.x >> 5;   // r = 0..7
  for (int rr = r; rr < 32; rr += 8)
    t[rr][c] = in[(size_t)(m0 + rr) * F + f0 + c];
  __syncthreads();
  for (int rr = r; rr < 32; rr += 8)
    out[(size_t)(f0 + rr) * M + m0 + c] = f2bf(t[c][rr]);
}

// s_i = Wh_i . a[:F], d_i = Wh_i . a[F:] (Wh fp32, a raw), + global Dmax.
__global__ __launch_bounds__(256) void sd_f32(const float* __restrict__ Wh,
    const void* __restrict__ a2, float* __restrict__ s, float* __restrict__ d,
    unsigned* __restrict__ cell, int F, const unsigned* __restrict__ modep) {
  int f32 = (int)*modep;
  int row = blockIdx.x * 4 + (threadIdx.x >> 6);
  int l = threadIdx.x & 63;
  float ss = 0.f, dd = 0.f;
  for (int k = l; k < F; k += 64) {
    float wv = Wh[(size_t)row * F + k];
    ss += wv * ldf(a2, k, f32);
    dd += wv * ldf(a2, F + k, f32);
  }
#pragma unroll
  for (int off = 32; off > 0; off >>= 1) {
    ss += __shfl_down(ss, off, 64);
    dd += __shfl_down(dd, off, 64);
  }
  if (l == 0) {
    s[row] = ss; d[row] = dd;
    atomicMax(cell, fkey(dd));
  }
}

// swizzled P-fragment LDS byte offset: [L][s][mh][row 0..15][kg 0..3] x 8 bf16
// kg XOR'd with (row>>1)&3 so both b128 writes (score) and reads (PV) spread
// evenly over the 8 bank-quads (2-way residual = free).
__device__ __forceinline__ int pa_off(int L, int s, int mh, int row, int kg) {
  return ((L * 4 + s * 2 + mh) << 10) + (row << 6) + ((kg ^ ((row >> 1) & 3)) << 4);
}

// Flash GAT layer(s) on MFMA. R=32 rows/block, 64-j tile per iteration.
// NL=1: FDIM=256, 4 waves x 4 n-tiles (layer a only).
// NL=2: FDIM=64, waves 0-1 -> layer a, waves 2-3 -> layer b, 2 n-tiles each
//       (fuses mu/lv: one adjacency pass for both layers).
// Accumulates UNNORMALIZED row sums into acc*/ls* via atomicAdd (pre-zeroed).
template <int NL, int FDIM, int JS>
__global__ __launch_bounds__(256) void flash_mfma(
    const u16* __restrict__ whTa, const u16* __restrict__ whTb,   // bf16 [FDIM][NROW]
    const float* __restrict__ sa, const float* __restrict__ da,
    const float* __restrict__ sb, const float* __restrict__ db,
    const unsigned* __restrict__ cella, const unsigned* __restrict__ cellb,
    const void* __restrict__ adj, const unsigned* __restrict__ amodep,
    float* __restrict__ acca, float* __restrict__ lsa,
    float* __restrict__ accb, float* __restrict__ lsb) {
  constexpr int JLEN = NROW / JS;
  constexpr int NIT = JLEN / 64;
  constexpr int NTW = (NL == 1) ? 4 : 2;     // n-tiles per wave
  __shared__ __align__(16) char PA[NL * 4096];   // bf16 P fragments (2 k-steps)
  __shared__ float ddl[2][NL][64];               // d_j double-buffer
  __shared__ float sv_[NL][32], Ms_[NL][32];
  int tid = threadIdx.x;
  int amode = (int)*amodep;
  int rblk = blockIdx.x / JS, js = blockIdx.x - rblk * JS;
  int r0 = rblk * 32;
  size_t jbase = (size_t)js * JLEN;
  if (tid < 32 * NL) {
    int L = tid >> 5, i = tid & 31;
    float Dm = fkeydec(L ? *cellb : *cella);
    float t0 = (L ? sb : sa)[r0 + i];
    sv_[L][i] = t0;
    float m = t0 + Dm;
    Ms_[L][i] = fmaxf(m, 0.2f * m);   // lrelu(s_i + Dmax) >= all e[i,:]
  }
  if (tid < 64 * NL) {
    int L = tid >> 6, i = tid & 63;
    ddl[0][L][i] = (L ? db : da)[jbase + i];
  }
  __syncthreads();
  // score-phase mapping: 32 rows x 8 j-octets
  int sr = tid >> 3, sjo = tid & 7;
  int s_w = sjo >> 2, kg_w = sjo & 3, mh_w = sr >> 4, row_w = sr & 15;
  // PV-phase mapping
  int l = tid & 63, w = tid >> 6;
  int layer = (NL == 1) ? 0 : (w >> 1);
  int ntb = (NL == 1) ? (w * 4) : ((w & 1) * 2);
  const u16* whT = layer ? whTb : whTa;
  f32x4 acc[2][NTW];
#pragma unroll
  for (int m = 0; m < 2; ++m)
#pragma unroll
    for (int n = 0; n < NTW; ++n) acc[m][n] = (f32x4){0.f, 0.f, 0.f, 0.f};
  float psum[NL];
#pragma unroll
  for (int L = 0; L < NL; ++L) psum[L] = 0.f;
  size_t abase = (size_t)(r0 + sr) * NROW + jbase + sjo * 8;

  for (int it = 0; it < NIT; ++it) {
    size_t j0 = jbase + (size_t)it * 64;
    int cur = it & 1;
    if (it + 1 < NIT && tid < 64 * NL) {      // prefetch next tile's d_j
      int L = tid >> 6, i = tid & 63;
      ddl[cur ^ 1][L][i] = (L ? db : da)[j0 + 64 + i];
    }
    // ---- score phase: P[r, j0+sjo*8 .. +7] in bf16, j-contiguous b128 store
    int aa[8];
    mask8(adj, abase + (size_t)it * 64, amode, aa);
#pragma unroll
    for (int L = 0; L < NL; ++L) {
      float sv = sv_[L][sr], Mr = Ms_[L][sr];
      short8 pk;
      float ps = 0.f;
#pragma unroll
      for (int q = 0; q < 8; ++q) {
        float t = sv + ddl[cur][L][sjo * 8 + q];
        float e = fmaxf(t, 0.2f * t) - Mr;           // <= 0
        float p = aa[q] ? __expf(e) : 0.f;
        ps += p;
        pk[q] = (short)f2bf(p);
      }
      psum[L] += ps;
      *(short8*)(PA + pa_off(L, s_w, mh_w, row_w, kg_w)) = pk;
    }
    __syncthreads();                  // PA ready
    // ---- PV phase: out[r0..+32, wave n-range] += P * WhT^T  (MFMA)
#pragma unroll
    for (int s2 = 0; s2 < 2; ++s2) {
      short8 a0 = *(const short8*)(PA + pa_off(layer, s2, 0, l & 15, l >> 4));
      short8 a1 = *(const short8*)(PA + pa_off(layer, s2, 1, l & 15, l >> 4));
      size_t jcol = j0 + s2 * 32 + (size_t)(l >> 4) * 8;
#pragma unroll
      for (int nt = 0; nt < NTW; ++nt) {
        short8 b = *(const short8*)&whT[(size_t)((ntb + nt) * 16 + (l & 15)) * NROW + jcol];
        acc[0][nt] = __builtin_amdgcn_mfma_f32_16x16x32_bf16(a0, b, acc[0][nt], 0, 0, 0);
        acc[1][nt] = __builtin_amdgcn_mfma_f32_16x16x32_bf16(a1, b, acc[1][nt], 0, 0, 0);
      }
    }
    __syncthreads();                  // PA free for next score phase
  }
  // ---- lsum: per-thread psum -> LDS (reuse PA) -> one atomic per row
  float* red = (float*)PA;
#pragma unroll
  for (int L = 0; L < NL; ++L) red[L * 256 + sr * 8 + sjo] = psum[L];
  __syncthreads();
  if (tid < 32 * NL) {
    int L = tid >> 5, r = tid & 31;
    float t = 0.f;
#pragma unroll
    for (int q = 0; q < 8; ++q) t += red[L * 256 + r * 8 + q];
    atomicAdd(&(L ? lsb : lsa)[r0 + r], t);
  }
  // ---- accumulator flush (C/D layout: col=lane&15, row=(lane>>4)*4+reg)
  float* accp = layer ? accb : acca;
#pragma unroll
  for (int m = 0; m < 2; ++m)
#pragma unroll
    for (int nt = 0; nt < NTW; ++nt)
#pragma unroll
      for (int q = 0; q < 4; ++q)
        atomicAdd(&accp[(size_t)(r0 + m * 16 + (l >> 4) * 4 + q) * FDIM +
                        (ntb + nt) * 16 + (l & 15)],
                  acc[m][nt][q]);
}

// h = elu(acc/lsum) fp32 (layer 1). n = 8192*256.
__global__ __launch_bounds__(256) void combine_elu(const float* __restrict__ acc_g,
    const float* __restrict__ lsum_g, float* __restrict__ h) {
  int idx = blockIdx.x * 256 + threadIdx.x;
  float x = acc_g[idx] / lsum_g[idx >> 8];
  h[idx] = (x > 0.f) ? x : (__expf(x) - 1.f);
}

// out = acc/lsum fp32, dual store (ws buffer + d_out region). n = 8192*64.
__global__ __launch_bounds__(256) void combine_div(const float* __restrict__ acc_g,
    const float* __restrict__ lsum_g, float* __restrict__ outf, float* __restrict__ outd) {
  int idx = blockIdx.x * 256 + threadIdx.x;
  float x = acc_g[idx] / lsum_g[idx >> 6];
  outf[idx] = x;
  outd[idx] = x;
}

// logits = (mu + eps*exp(0.5*logvar)) @ Wc + bc (mu/lv fp32, rest raw). fp32 out.
__global__ __launch_bounds__(256) void logits_f32(const float* __restrict__ mu,
    const float* __restrict__ lv, const void* __restrict__ eps,
    const void* __restrict__ Wc, const void* __restrict__ bcv,
    float* __restrict__ outL, const unsigned* __restrict__ modep) {
  int f32 = (int)*modep;
  __shared__ float zs[64 * 64];
  __shared__ float wcs[64 * 16];
  int tid = threadIdx.x;
  for (int i = tid; i < 1024; i += 256) wcs[i] = ldf(Wc, i, f32);
  int rl = tid >> 2, cs = (tid & 3) * 16;
  int row = blockIdx.x * 64 + rl;
  size_t rb64 = (size_t)row * 64;
  for (int c = cs; c < cs + 16; ++c)
    zs[rl * 64 + c] = mu[rb64 + c] + ldf(eps, rb64 + c, f32) * __expf(0.5f * lv[rb64 + c]);
  __syncthreads();
  for (int it = tid; it < 1024; it += 256) {
    int r = it >> 4, oc = it & 15;
    float a = ldf(bcv, oc, f32);
    for (int c = 0; c < 64; ++c) a += zs[r * 64 + c] * wcs[c * 16 + oc];
    outL[(size_t)(blockIdx.x * 64 + r) * 16 + oc] = a;
  }
}

extern "C" void kernel_launch(void* const* d_in, const int* in_sizes, int n_in,
                              void* d_out, int out_size, void* d_ws, size_t ws_size,
                              hipStream_t stream) {
  (void)out_size; (void)ws_size;
  // ---- size-based input resolution (robust to permutation; ties in dict order)
  int ix = 0, iadj = 1, ieps = 2, iW1 = 3, ia1 = 4, iWmu = 5, iamu = 6,
      iWlv = 7, ialv = 8, iWc = 9, ibc = 10;
  {
    int fmu = -1, flv = -1, fam = -1, fal = -1;
    for (int i = 0; i < n_in; ++i) {
      switch (in_sizes[i]) {
        case 67108864: iadj = i; break;
        case 4194304:  ix   = i; break;
        case 524288:   ieps = i; break;
        case 131072:   iW1  = i; break;
        case 512:      ia1  = i; break;
        case 1024:     iWc  = i; break;
        case 16:       ibc  = i; break;
        case 16384:    if (fmu < 0) fmu = i; else flv = i; break;
        case 128:      if (fam < 0) fam = i; else fal = i; break;
        default: break;
      }
    }
    if (fmu >= 0 && flv >= 0) { iWmu = fmu; iWlv = flv; }
    if (fam >= 0 && fal >= 0) { iamu = fam; ialv = fal; }
  }
  const void* adj = d_in[iadj];
  char* ws = (char*)d_ws;
  const size_t KB = 1024, MB = 1024 * 1024;
  // ---- workspace (<= 24.6 MB) ----
  float* wh1   = (float*)(ws + 0);                 // 8MB [dead after flash1/transpose1]
  float* whmu  = (float*)(ws + 0);                 // 2MB [overlay]
  float* whlv  = (float*)(ws + 2 * MB);            // 2MB [overlay]
  float* muf   = (float*)(ws + 4 * MB);            // 2MB [overlay]
  float* lvf   = (float*)(ws + 6 * MB);            // 2MB [overlay]
  u16*   whT1  = (u16*)(ws + 8 * MB);              // 4MB bf16 [256][8192], dead after flash1
  float* h     = (float*)(ws + 8 * MB);            // 8MB [overlay, written after whT1 dead]
  float* hacc  = (float*)(ws + 16 * MB);           // 8MB [dead after combine1]
  float* macc  = (float*)(ws + 16 * MB);           // 2MB [overlay, memset mid-stream]
  float* lvacc = (float*)(ws + 18 * MB);           // 2MB [overlay, memset mid-stream]
  u16*   whmuT = (u16*)(ws + 20 * MB);             // 1MB bf16 [64][8192] [overlay]
  u16*   whlvT = (u16*)(ws + 21 * MB);             // 1MB bf16 [64][8192] [overlay]
  float* lsum1 = (float*)(ws + 24 * MB);           // 32KB
  float* lsmu  = (float*)(ws + 24 * MB + 32 * KB);
  float* lslv  = (float*)(ws + 24 * MB + 64 * KB);
  float* s1    = (float*)(ws + 24 * MB + 96 * KB);
  float* d1    = (float*)(ws + 24 * MB + 128 * KB);
  float* smu   = (float*)(ws + 24 * MB + 160 * KB);
  float* dmu   = (float*)(ws + 24 * MB + 192 * KB);
  float* slv   = (float*)(ws + 24 * MB + 224 * KB);
  float* dlv   = (float*)(ws + 24 * MB + 256 * KB);
  unsigned* dmx   = (unsigned*)(ws + 24 * MB + 288 * KB);  // 4 cells
  unsigned* mode  = (unsigned*)(ws + 24 * MB + 289 * KB);
  unsigned* amode = (unsigned*)(ws + 24 * MB + 290 * KB);

  // fp32 output layout: [logits 8192*16 | mu 8192*64 | logvar 8192*64]
  float* out_logits = (float*)d_out;
  float* out_mu     = (float*)d_out + 131072;
  float* out_lv     = (float*)d_out + 655360;

  (void)hipMemsetAsync(dmx, 0, 16, stream);
  (void)hipMemsetAsync(lsum1, 0, 96 * KB, stream);        // lsum1+lsmu+lslv
  (void)hipMemsetAsync(hacc, 0, 8 * MB, stream);
  detect3<<<1, 256, 0, stream>>>((const u16*)d_in[ix], mode);
  detect_adj<<<1, 256, 0, stream>>>((const unsigned*)adj, amode);

  // layer 1: Wh1 = x @ W1 (fp32), WhT1 (bf16), s/d, MFMA flash (JS=2), combine+elu
  gemm_f32<<<dim3(4, 128), 256, 0, stream>>>(d_in[ix], d_in[iW1], wh1, 512, 256, mode, 1, 1);
  transpose_bf16<<<dim3(256, 8), 256, 0, stream>>>(wh1, whT1, 8192, 256);
  sd_f32<<<2048, 256, 0, stream>>>(wh1, d_in[ia1], s1, d1, dmx + 0, 256, mode);
  flash_mfma<1, 256, 2><<<512, 256, 0, stream>>>(whT1, nullptr, s1, d1,
      nullptr, nullptr, dmx + 0, nullptr, adj, amode, hacc, lsum1, nullptr, nullptr);
  combine_elu<<<8192, 256, 0, stream>>>(hacc, lsum1, h);

  // zero layer-2/3 accumulators (overlaying dead hacc; stream-ordered)
  (void)hipMemsetAsync(macc, 0, 4 * MB, stream);          // macc + lvacc

  // layers 2/3: whmu/whlv = h @ W, transposed bf16 copies, s/d, FUSED MFMA flash
  gemm_f32<<<dim3(1, 128), 256, 0, stream>>>(h, d_in[iWmu], whmu, 256, 64, mode, 0, 1);
  gemm_f32<<<dim3(1, 128), 256, 0, stream>>>(h, d_in[iWlv], whlv, 256, 64, mode, 0, 1);
  transpose_bf16<<<dim3(256, 2), 256, 0, stream>>>(whmu, whmuT, 8192, 64);
  transpose_bf16<<<dim3(256, 2), 256, 0, stream>>>(whlv, whlvT, 8192, 64);
  sd_f32<<<2048, 256, 0, stream>>>(whmu, d_in[iamu], smu, dmu, dmx + 1, 64, mode);
  sd_f32<<<2048, 256, 0, stream>>>(whlv, d_in[ialv], slv, dlv, dmx + 2, 64, mode);
  flash_mfma<2, 64, 4><<<1024, 256, 0, stream>>>(whmuT, whlvT, smu, dmu, slv, dlv,
      dmx + 1, dmx + 2, adj, amode, macc, lsmu, lvacc, lslv);
  combine_div<<<2048, 256, 0, stream>>>(macc, lsmu, muf, out_mu);
  combine_div<<<2048, 256, 0, stream>>>(lvacc, lslv, lvf, out_lv);

  logits_f32<<<128, 256, 0, stream>>>(muf, lvf, d_in[ieps], d_in[iWc], d_in[ibc], out_logits, mode);
}

// Round 2
// 1015.342 us; speedup vs baseline: 2.0512x; 1.1863x over previous
//
#include <hip/hip_runtime.h>

typedef unsigned short u16;
typedef __attribute__((ext_vector_type(8))) short short8;
typedef __attribute__((ext_vector_type(4))) float f32x4;

#define NROW 8192

__device__ __forceinline__ float bf2f(u16 h) {
  unsigned u = ((unsigned)h) << 16;
  return __builtin_bit_cast(float, u);
}
// mode-aware load: f32 ? fp32 storage : bf16 storage (upcast)
__device__ __forceinline__ float ldf(const void* p, size_t i, int f32) {
  return f32 ? ((const float*)p)[i] : bf2f(((const u16*)p)[i]);
}
// fp32 -> bf16 round-to-nearest-even
__device__ __forceinline__ u16 f2bf(float f) {
  unsigned b = __builtin_bit_cast(unsigned, f);
  b += 0x7FFFu + ((b >> 16) & 1u);
  return (u16)(b >> 16);
}
// order-preserving float->uint key for atomicMax
__device__ __forceinline__ unsigned fkey(float f) {
  unsigned b = __builtin_bit_cast(unsigned, f);
  return (b & 0x80000000u) ? ~b : (b | 0x80000000u);
}
__device__ __forceinline__ float fkeydec(unsigned k) {
  unsigned b = (k & 0x80000000u) ? (k & 0x7FFFFFFFu) : ~k;
  return __builtin_bit_cast(float, b);
}

// ---- storage-dtype detection on x (N(0,1)).
__global__ void detect3(const u16* __restrict__ xr, unsigned* __restrict__ mode) {
  __shared__ int zc, bg;
  int t = threadIdx.x;   // 256
  if (t == 0) { zc = 0; bg = 0; }
  __syncthreads();
  int zeros_even = 0; int big = 0;
  for (int i = t; i < 4096; i += 256) {
    u16 v = xr[i];
    if (!(i & 1) && v == 0) zeros_even++;
    if (fabsf(bf2f(v)) > 1e6f) big = 1;
  }
  atomicAdd(&zc, zeros_even);
  if (big) atomicOr(&bg, 1);
  __syncthreads();
  if (t == 0) *mode = (zc > 512 || bg) ? 1u : 0u;   // 1 = fp32 storage
}

// ---- adj storage detection (u32 pair pattern 0x00003F80 unique to bf16).
__global__ void detect_adj(const unsigned* __restrict__ a, unsigned* __restrict__ amode) {
  __shared__ int clo;
  int t = threadIdx.x;   // 256
  if (t == 0) clo = 0;
  __syncthreads();
  int c = 0;
  for (int i = t; i < 4096; i += 256)
    if (a[i] == 0x00003F80u) c++;
  atomicAdd(&clo, c);
  __syncthreads();
  if (t == 0) *amode = (clo > 32) ? 1u : 0u;   // 1 = bf16 storage
}

// ---- raw adjacency octet (8 elements), load/decode split for prefetching
struct AdjRaw { int4 w0, w1; };
__device__ __forceinline__ AdjRaw adj_load(const void* adj, size_t base, int amode) {
  AdjRaw r;
  if (amode == 0) {          // u32 per element: 32B
    const int4* p = (const int4*)((const int*)adj + base);
    r.w0 = p[0]; r.w1 = p[1];
  } else {                   // u16 per element: 16B
    r.w0 = *(const int4*)((const u16*)adj + base);
    r.w1 = make_int4(0, 0, 0, 0);
  }
  return r;
}
__device__ __forceinline__ void adj_decode(const AdjRaw& r, int amode, int* aa) {
  if (amode == 0) {
    aa[0] = r.w0.x != 0; aa[1] = r.w0.y != 0; aa[2] = r.w0.z != 0; aa[3] = r.w0.w != 0;
    aa[4] = r.w1.x != 0; aa[5] = r.w1.y != 0; aa[6] = r.w1.z != 0; aa[7] = r.w1.w != 0;
  } else {
    aa[0] = (r.w0.x & 0xFFFF) != 0; aa[1] = ((unsigned)r.w0.x >> 16) != 0;
    aa[2] = (r.w0.y & 0xFFFF) != 0; aa[3] = ((unsigned)r.w0.y >> 16) != 0;
    aa[4] = (r.w0.z & 0xFFFF) != 0; aa[5] = ((unsigned)r.w0.z >> 16) != 0;
    aa[6] = (r.w0.w & 0xFFFF) != 0; aa[7] = ((unsigned)r.w0.w >> 16) != 0;
  }
}

// C[M x N] fp32 = A[M x K] @ B[K x N]; A/B raw (mode-aware) or fp32 ws buffers.
// (scalar path; layer-2/3 only)
__global__ __launch_bounds__(256) void gemm_f32(const void* __restrict__ A,
    const void* __restrict__ B, float* __restrict__ C, int K, int N,
    const unsigned* __restrict__ modep, int araw, int braw) {
  int f32a = araw ? (int)*modep : 1;
  int f32b = braw ? (int)*modep : 1;
  __shared__ float sA[16][68];
  __shared__ float sB[16][68];
  int tid = threadIdx.x;
  int rb = blockIdx.y, cb = blockIdx.x;
  int tx = tid & 15, ty = tid >> 4;
  float acc[4][4] = {};
  for (int kt = 0; kt < K; kt += 16) {
    __syncthreads();
#pragma unroll
    for (int it = 0; it < 4; ++it) {
      int idx = tid + it * 256;          // 0..1023
      // A: consecutive lanes read consecutive k (coalesced 64B segments)
      int ka = idx & 15, ma = idx >> 4;
      sA[ka][ma] = ldf(A, (size_t)(rb * 64 + ma) * K + kt + ka, f32a);
      // B: consecutive lanes read consecutive n (already coalesced)
      int mb = idx & 63, kb = idx >> 6;
      sB[kb][mb] = ldf(B, (size_t)(kt + kb) * N + cb * 64 + mb, f32b);
    }
    __syncthreads();
#pragma unroll
    for (int k = 0; k < 16; ++k) {
      float4 av = *(const float4*)&sA[k][ty * 4];
      float4 bv = *(const float4*)&sB[k][tx * 4];
      float aa[4] = {av.x, av.y, av.z, av.w};
      float bb[4] = {bv.x, bv.y, bv.z, bv.w};
#pragma unroll
      for (int r = 0; r < 4; ++r)
#pragma unroll
        for (int c = 0; c < 4; ++c) acc[r][c] += aa[r] * bb[c];
    }
  }
#pragma unroll
  for (int r = 0; r < 4; ++r)
#pragma unroll
    for (int c = 0; c < 4; ++c)
      C[(size_t)(rb * 64 + ty * 4 + r) * N + cb * 64 + tx * 4 + c] = acc[r][c];
}

// C[M x N] fp32 = Abf[M x K] @ BT[N x K]^T, all bf16 operands, MFMA, no LDS.
// grid (N/64, M/64), 256 threads; wave w owns rows w*16..+15, 4 n-tiles.
__global__ __launch_bounds__(256) void gemm_mfma(const u16* __restrict__ Abf,
    const u16* __restrict__ BT, float* __restrict__ C, int K, int N) {
  int tid = threadIdx.x;
  int l = tid & 63, w = tid >> 6;
  int m0 = blockIdx.y * 64, n0 = blockIdx.x * 64;
  const u16* arow = Abf + (size_t)(m0 + w * 16 + (l & 15)) * K + (l >> 4) * 8;
  const u16* brow = BT + (size_t)(n0 + (l & 15)) * K + (l >> 4) * 8;
  f32x4 acc[4];
#pragma unroll
  for (int nt = 0; nt < 4; ++nt) acc[nt] = (f32x4){0.f, 0.f, 0.f, 0.f};
  for (int k0 = 0; k0 < K; k0 += 32) {
    short8 a = *(const short8*)(arow + k0);
#pragma unroll
    for (int nt = 0; nt < 4; ++nt) {
      short8 b = *(const short8*)(brow + (size_t)nt * 16 * K + k0);
      acc[nt] = __builtin_amdgcn_mfma_f32_16x16x32_bf16(a, b, acc[nt], 0, 0, 0);
    }
  }
  // C/D layout: col = lane&15, row = (lane>>4)*4 + q
#pragma unroll
  for (int nt = 0; nt < 4; ++nt)
#pragma unroll
    for (int q = 0; q < 4; ++q)
      C[(size_t)(m0 + w * 16 + (l >> 4) * 4 + q) * N + n0 + nt * 16 + (l & 15)] =
          acc[nt][q];
}

// bf16 copy of a mode-aware buffer (8 elems/thread). n8 = elems/8.
__global__ __launch_bounds__(256) void convert_bf16(const void* __restrict__ in,
    u16* __restrict__ out, int n8, const unsigned* __restrict__ modep) {
  int f32 = (int)*modep;
  int i = blockIdx.x * 256 + threadIdx.x;
  if (i >= n8) return;
  if (f32) {
    float4 v0 = ((const float4*)in)[(size_t)i * 2];
    float4 v1 = ((const float4*)in)[(size_t)i * 2 + 1];
    ushort4 o0 = {f2bf(v0.x), f2bf(v0.y), f2bf(v0.z), f2bf(v0.w)};
    ushort4 o1 = {f2bf(v1.x), f2bf(v1.y), f2bf(v1.z), f2bf(v1.w)};
    ((ushort4*)out)[(size_t)i * 2] = o0;
    ((ushort4*)out)[(size_t)i * 2 + 1] = o1;
  } else {
    ((int4*)out)[i] = ((const int4*)in)[i];   // already bf16: raw copy
  }
}

// transpose + bf16 convert: in fp32 [M][F] -> out bf16 [F][M]. grid (M/32, F/32).
__global__ __launch_bounds__(256) void transpose_bf16(const float* __restrict__ in,
    u16* __restrict__ out, int M, int F) {
  __shared__ float t[32][33];
  int m0 = blockIdx.x * 32, f0 = blockIdx.y * 32;
  int c = threadIdx.x & 31, r = threadIdx.x >> 5;   // r = 0..7
  for (int rr = r; rr < 32; rr += 8)
    t[rr][c] = in[(size_t)(m0 + rr) * F + f0 + c];
  __syncthreads();
  for (int rr = r; rr < 32; rr += 8)
    out[(size_t)(f0 + rr) * M + m0 + c] = f2bf(t[c][rr]);
}

// transpose + bf16 convert from a RAW (mode-aware) buffer. grid (M/32, F/32).
__global__ __launch_bounds__(256) void transpose_any(const void* __restrict__ in,
    u16* __restrict__ out, int M, int F, const unsigned* __restrict__ modep) {
  int f32 = (int)*modep;
  __shared__ u16 t[32][33];
  int m0 = blockIdx.x * 32, f0 = blockIdx.y * 32;
  int c = threadIdx.x & 31, r = threadIdx.x >> 5;
  for (int rr = r; rr < 32; rr += 8)
    t[rr][c] = f2bf(ldf(in, (size_t)(m0 + rr) * F + f0 + c, f32));
  __syncthreads();
  for (int rr = r; rr < 32; rr += 8)
    out[(size_t)(f0 + rr) * M + m0 + c] = t[c][rr];
}

// s_i = Wh_i . a[:F], d_i = Wh_i . a[F:] (Wh fp32, a raw), + global Dmax.
__global__ __launch_bounds__(256) void sd_f32(const float* __restrict__ Wh,
    const void* __restrict__ a2, float* __restrict__ s, float* __restrict__ d,
    unsigned* __restrict__ cell, int F, const unsigned* __restrict__ modep) {
  int f32 = (int)*modep;
  int row = blockIdx.x * 4 + (threadIdx.x >> 6);
  int l = threadIdx.x & 63;
  float ss = 0.f, dd = 0.f;
  for (int k = l; k < F; k += 64) {
    float wv = Wh[(size_t)row * F + k];
    ss += wv * ldf(a2, k, f32);
    dd += wv * ldf(a2, F + k, f32);
  }
#pragma unroll
  for (int off = 32; off > 0; off >>= 1) {
    ss += __shfl_down(ss, off, 64);
    dd += __shfl_down(dd, off, 64);
  }
  if (l == 0) {
    s[row] = ss; d[row] = dd;
    atomicMax(cell, fkey(dd));
  }
}

// swizzled P-fragment LDS byte offset: [L][s][mh][row 0..15][kg 0..3] x 8 bf16
__device__ __forceinline__ int pa_off(int L, int s, int mh, int row, int kg) {
  return ((L * 4 + s * 2 + mh) << 10) + (row << 6) + ((kg ^ ((row >> 1) & 3)) << 4);
}

// Flash GAT layer(s) on MFMA. R=32 rows/block, 64-j tile per iteration.
// Software-pipelined: adj prefetched 1 iter ahead (reg), B frags hoisted to
// score phase, d_j double-buffered in LDS.
template <int NL, int FDIM, int JS>
__global__ __launch_bounds__(256) void flash_mfma(
    const u16* __restrict__ whTa, const u16* __restrict__ whTb,   // bf16 [FDIM][NROW]
    const float* __restrict__ sa, const float* __restrict__ da,
    const float* __restrict__ sb, const float* __restrict__ db,
    const unsigned* __restrict__ cella, const unsigned* __restrict__ cellb,
    const void* __restrict__ adj, const unsigned* __restrict__ amodep,
    float* __restrict__ acca, float* __restrict__ lsa,
    float* __restrict__ accb, float* __restrict__ lsb) {
  constexpr int JLEN = NROW / JS;
  constexpr int NIT = JLEN / 64;
  constexpr int NTW = (NL == 1) ? 4 : 2;     // n-tiles per wave
  __shared__ __align__(16) char PA[NL * 4096];   // bf16 P fragments (2 k-steps)
  __shared__ float ddl[2][NL][64];               // d_j double-buffer
  __shared__ float sv_[NL][32], Ms_[NL][32];
  int tid = threadIdx.x;
  int amode = (int)*amodep;
  int rblk = blockIdx.x / JS, js = blockIdx.x - rblk * JS;
  int r0 = rblk * 32;
  size_t jbase = (size_t)js * JLEN;
  if (tid < 32 * NL) {
    int L = tid >> 5, i = tid & 31;
    float Dm = fkeydec(L ? *cellb : *cella);
    float t0 = (L ? sb : sa)[r0 + i];
    sv_[L][i] = t0;
    float m = t0 + Dm;
    Ms_[L][i] = fmaxf(m, 0.2f * m);   // lrelu(s_i + Dmax) >= all e[i,:]
  }
  if (tid < 64 * NL) {
    int L = tid >> 6, i = tid & 63;
    ddl[0][L][i] = (L ? db : da)[jbase + i];
  }
  __syncthreads();
  // score-phase mapping: 32 rows x 8 j-octets
  int sr = tid >> 3, sjo = tid & 7;
  int s_w = sjo >> 2, kg_w = sjo & 3, mh_w = sr >> 4, row_w = sr & 15;
  // PV-phase mapping
  int l = tid & 63, w = tid >> 6;
  int layer = (NL == 1) ? 0 : (w >> 1);
  int ntb = (NL == 1) ? (w * 4) : ((w & 1) * 2);
  const u16* whT = layer ? whTb : whTa;
  f32x4 acc[2][NTW];
#pragma unroll
  for (int m = 0; m < 2; ++m)
#pragma unroll
    for (int n = 0; n < NTW; ++n) acc[m][n] = (f32x4){0.f, 0.f, 0.f, 0.f};
  float psum[NL];
#pragma unroll
  for (int L = 0; L < NL; ++L) psum[L] = 0.f;
  size_t abase = (size_t)(r0 + sr) * NROW + jbase + sjo * 8;

  AdjRaw araw = adj_load(adj, abase, amode);          // it = 0
  for (int it = 0; it < NIT; ++it) {
    size_t j0 = jbase + (size_t)it * 64;
    int cur = it & 1;
    if (it + 1 < NIT && tid < 64 * NL) {              // prefetch next tile's d_j
      int L = tid >> 6, i = tid & 63;
      ddl[cur ^ 1][L][i] = (L ? db : da)[j0 + 64 + i];
    }
    // issue this tile's B fragments early (consumed in PV phase; L2-latency
    // hidden under score compute + barrier)
    short8 bfr[2][NTW];
#pragma unroll
    for (int s2 = 0; s2 < 2; ++s2) {
      size_t jcol = j0 + s2 * 32 + (size_t)(l >> 4) * 8;
#pragma unroll
      for (int nt = 0; nt < NTW; ++nt)
        bfr[s2][nt] =
            *(const short8*)&whT[(size_t)((ntb + nt) * 16 + (l & 15)) * NROW + jcol];
    }
    // prefetch next iteration's adjacency (HBM latency spans both barriers)
    AdjRaw anext = araw;
    if (it + 1 < NIT) anext = adj_load(adj, abase + (size_t)(it + 1) * 64, amode);
    int aa[8];
    adj_decode(araw, amode, aa);
    // ---- score phase: P[r, j0+sjo*8 .. +7] in bf16, j-contiguous b128 store
#pragma unroll
    for (int L = 0; L < NL; ++L) {
      float sv = sv_[L][sr], Mr = Ms_[L][sr];
      short8 pk;
      float ps = 0.f;
#pragma unroll
      for (int q = 0; q < 8; ++q) {
        float t = sv + ddl[cur][L][sjo * 8 + q];
        float e = fmaxf(t, 0.2f * t) - Mr;           // <= 0
        float p = aa[q] ? __expf(e) : 0.f;
        ps += p;
        pk[q] = (short)f2bf(p);
      }
      psum[L] += ps;
      *(short8*)(PA + pa_off(L, s_w, mh_w, row_w, kg_w)) = pk;
    }
    __syncthreads();                  // PA ready
    // ---- PV phase: out[r0..+32, wave n-range] += P * WhT^T  (MFMA)
#pragma unroll
    for (int s2 = 0; s2 < 2; ++s2) {
      short8 a0 = *(const short8*)(PA + pa_off(layer, s2, 0, l & 15, l >> 4));
      short8 a1 = *(const short8*)(PA + pa_off(layer, s2, 1, l & 15, l >> 4));
#pragma unroll
      for (int nt = 0; nt < NTW; ++nt) {
        acc[0][nt] = __builtin_amdgcn_mfma_f32_16x16x32_bf16(a0, bfr[s2][nt],
                                                             acc[0][nt], 0, 0, 0);
        acc[1][nt] = __builtin_amdgcn_mfma_f32_16x16x32_bf16(a1, bfr[s2][nt],
                                                             acc[1][nt], 0, 0, 0);
      }
    }
    __syncthreads();                  // PA free for next score phase
    araw = anext;
  }
  // ---- lsum: per-thread psum -> LDS (reuse PA) -> one atomic per row
  float* red = (float*)PA;
#pragma unroll
  for (int L = 0; L < NL; ++L) red[L * 256 + sr * 8 + sjo] = psum[L];
  __syncthreads();
  if (tid < 32 * NL) {
    int L = tid >> 5, r = tid & 31;
    float t = 0.f;
#pragma unroll
    for (int q = 0; q < 8; ++q) t += red[L * 256 + r * 8 + q];
    atomicAdd(&(L ? lsb : lsa)[r0 + r], t);
  }
  // ---- accumulator flush (C/D layout: col=lane&15, row=(lane>>4)*4+reg)
  float* accp = layer ? accb : acca;
#pragma unroll
  for (int m = 0; m < 2; ++m)
#pragma unroll
    for (int nt = 0; nt < NTW; ++nt)
#pragma unroll
      for (int q = 0; q < 4; ++q)
        atomicAdd(&accp[(size_t)(r0 + m * 16 + (l >> 4) * 4 + q) * FDIM +
                        (ntb + nt) * 16 + (l & 15)],
                  acc[m][nt][q]);
}

// h = elu(acc/lsum) fp32 (layer 1). n = 8192*256.
__global__ __launch_bounds__(256) void combine_elu(const float* __restrict__ acc_g,
    const float* __restrict__ lsum_g, float* __restrict__ h) {
  int idx = blockIdx.x * 256 + threadIdx.x;
  float x = acc_g[idx] / lsum_g[idx >> 8];
  h[idx] = (x > 0.f) ? x : (__expf(x) - 1.f);
}

// out = acc/lsum fp32, dual store (ws buffer + d_out region). n = 8192*64.
__global__ __launch_bounds__(256) void combine_div(const float* __restrict__ acc_g,
    const float* __restrict__ lsum_g, float* __restrict__ outf, float* __restrict__ outd) {
  int idx = blockIdx.x * 256 + threadIdx.x;
  float x = acc_g[idx] / lsum_g[idx >> 6];
  outf[idx] = x;
  outd[idx] = x;
}

// logits = (mu + eps*exp(0.5*logvar)) @ Wc + bc (mu/lv fp32, rest raw). fp32 out.
__global__ __launch_bounds__(256) void logits_f32(const float* __restrict__ mu,
    const float* __restrict__ lv, const void* __restrict__ eps,
    const void* __restrict__ Wc, const void* __restrict__ bcv,
    float* __restrict__ outL, const unsigned* __restrict__ modep) {
  int f32 = (int)*modep;
  __shared__ float zs[64 * 64];
  __shared__ float wcs[64 * 16];
  int tid = threadIdx.x;
  for (int i = tid; i < 1024; i += 256) wcs[i] = ldf(Wc, i, f32);
  int rl = tid >> 2, cs = (tid & 3) * 16;
  int row = blockIdx.x * 64 + rl;
  size_t rb64 = (size_t)row * 64;
  for (int c = cs; c < cs + 16; ++c)
    zs[rl * 64 + c] = mu[rb64 + c] + ldf(eps, rb64 + c, f32) * __expf(0.5f * lv[rb64 + c]);
  __syncthreads();
  for (int it = tid; it < 1024; it += 256) {
    int r = it >> 4, oc = it & 15;
    float a = ldf(bcv, oc, f32);
    for (int c = 0; c < 64; ++c) a += zs[r * 64 + c] * wcs[c * 16 + oc];
    outL[(size_t)(blockIdx.x * 64 + r) * 16 + oc] = a;
  }
}

extern "C" void kernel_launch(void* const* d_in, const int* in_sizes, int n_in,
                              void* d_out, int out_size, void* d_ws, size_t ws_size,
                              hipStream_t stream) {
  (void)out_size; (void)ws_size;
  // ---- size-based input resolution (robust to permutation; ties in dict order)
  int ix = 0, iadj = 1, ieps = 2, iW1 = 3, ia1 = 4, iWmu = 5, iamu = 6,
      iWlv = 7, ialv = 8, iWc = 9, ibc = 10;
  {
    int fmu = -1, flv = -1, fam = -1, fal = -1;
    for (int i = 0; i < n_in; ++i) {
      switch (in_sizes[i]) {
        case 67108864: iadj = i; break;
        case 4194304:  ix   = i; break;
        case 524288:   ieps = i; break;
        case 131072:   iW1  = i; break;
        case 512:      ia1  = i; break;
        case 1024:     iWc  = i; break;
        case 16:       ibc  = i; break;
        case 16384:    if (fmu < 0) fmu = i; else flv = i; break;
        case 128:      if (fam < 0) fam = i; else fal = i; break;
        default: break;
      }
    }
    if (fmu >= 0 && flv >= 0) { iWmu = fmu; iWlv = flv; }
    if (fam >= 0 && fal >= 0) { iamu = fam; ialv = fal; }
  }
  const void* adj = d_in[iadj];
  char* ws = (char*)d_ws;
  const size_t KB = 1024, MB = 1024 * 1024;
  // ---- workspace (<= 24.6 MB) ----
  float* wh1   = (float*)(ws + 0);                 // 8MB [dead after transpose1/sd1/flash1... actually flash reads whT1]
  float* whmu  = (float*)(ws + 0);                 // 2MB [overlay]
  float* whlv  = (float*)(ws + 2 * MB);            // 2MB [overlay]
  float* muf   = (float*)(ws + 4 * MB);            // 2MB [overlay]
  float* lvf   = (float*)(ws + 6 * MB);            // 2MB [overlay]
  u16*   xbf   = (u16*)(ws + 8 * MB);              // 8MB bf16 x [dead after gemm1]
  u16*   whT1  = (u16*)(ws + 8 * MB);              // 4MB bf16 [256][8192] [overlay on dead xbf]
  float* h     = (float*)(ws + 8 * MB);            // 8MB [overlay, written after whT1 dead]
  float* hacc  = (float*)(ws + 16 * MB);           // 8MB [dead after combine1]
  float* macc  = (float*)(ws + 16 * MB);           // 2MB [overlay, memset mid-stream]
  float* lvacc = (float*)(ws + 18 * MB);           // 2MB [overlay, memset mid-stream]
  u16*   whmuT = (u16*)(ws + 20 * MB);             // 1MB bf16 [64][8192] [overlay]
  u16*   whlvT = (u16*)(ws + 21 * MB);             // 1MB bf16 [64][8192] [overlay]
  u16*   W1T   = (u16*)(ws + 22 * MB);             // 256KB bf16 [256][512]
  float* lsum1 = (float*)(ws + 24 * MB);           // 32KB
  float* lsmu  = (float*)(ws + 24 * MB + 32 * KB);
  float* lslv  = (float*)(ws + 24 * MB + 64 * KB);
  float* s1    = (float*)(ws + 24 * MB + 96 * KB);
  float* d1    = (float*)(ws + 24 * MB + 128 * KB);
  float* smu   = (float*)(ws + 24 * MB + 160 * KB);
  float* dmu   = (float*)(ws + 24 * MB + 192 * KB);
  float* slv   = (float*)(ws + 24 * MB + 224 * KB);
  float* dlv   = (float*)(ws + 24 * MB + 256 * KB);
  unsigned* dmx   = (unsigned*)(ws + 24 * MB + 288 * KB);  // 4 cells
  unsigned* mode  = (unsigned*)(ws + 24 * MB + 289 * KB);
  unsigned* amode = (unsigned*)(ws + 24 * MB + 290 * KB);

  // fp32 output layout: [logits 8192*16 | mu 8192*64 | logvar 8192*64]
  float* out_logits = (float*)d_out;
  float* out_mu     = (float*)d_out + 131072;
  float* out_lv     = (float*)d_out + 655360;

  (void)hipMemsetAsync(dmx, 0, 16, stream);
  (void)hipMemsetAsync(lsum1, 0, 96 * KB, stream);        // lsum1+lsmu+lslv
  (void)hipMemsetAsync(hacc, 0, 8 * MB, stream);
  detect3<<<1, 256, 0, stream>>>((const u16*)d_in[ix], mode);
  detect_adj<<<1, 256, 0, stream>>>((const unsigned*)adj, amode);

  // layer 1: xbf/W1T bf16, Wh1 = xbf @ W1T^T (MFMA), WhT1 bf16, s/d,
  // MFMA flash (JS=8, 2048 blocks), combine+elu
  convert_bf16<<<2048, 256, 0, stream>>>(d_in[ix], xbf, 524288, mode);
  transpose_any<<<dim3(16, 8), 256, 0, stream>>>(d_in[iW1], W1T, 512, 256, mode);
  gemm_mfma<<<dim3(4, 128), 256, 0, stream>>>(xbf, W1T, wh1, 512, 256);
  transpose_bf16<<<dim3(256, 8), 256, 0, stream>>>(wh1, whT1, 8192, 256);
  sd_f32<<<2048, 256, 0, stream>>>(wh1, d_in[ia1], s1, d1, dmx + 0, 256, mode);
  flash_mfma<1, 256, 8><<<2048, 256, 0, stream>>>(whT1, nullptr, s1, d1,
      nullptr, nullptr, dmx + 0, nullptr, adj, amode, hacc, lsum1, nullptr, nullptr);
  combine_elu<<<8192, 256, 0, stream>>>(hacc, lsum1, h);

  // zero layer-2/3 accumulators (overlaying dead hacc; stream-ordered)
  (void)hipMemsetAsync(macc, 0, 4 * MB, stream);          // macc + lvacc

  // layers 2/3: whmu/whlv = h @ W, transposed bf16 copies, s/d, FUSED MFMA flash
  gemm_f32<<<dim3(1, 128), 256, 0, stream>>>(h, d_in[iWmu], whmu, 256, 64, mode, 0, 1);
  gemm_f32<<<dim3(1, 128), 256, 0, stream>>>(h, d_in[iWlv], whlv, 256, 64, mode, 0, 1);
  transpose_bf16<<<dim3(256, 2), 256, 0, stream>>>(whmu, whmuT, 8192, 64);
  transpose_bf16<<<dim3(256, 2), 256, 0, stream>>>(whlv, whlvT, 8192, 64);
  sd_f32<<<2048, 256, 0, stream>>>(whmu, d_in[iamu], smu, dmu, dmx + 1, 64, mode);
  sd_f32<<<2048, 256, 0, stream>>>(whlv, d_in[ialv], slv, dlv, dmx + 2, 64, mode);
  flash_mfma<2, 64, 8><<<2048, 256, 0, stream>>>(whmuT, whlvT, smu, dmu, slv, dlv,
      dmx + 1, dmx + 2, adj, amode, macc, lsmu, lvacc, lslv);
  combine_div<<<2048, 256, 0, stream>>>(macc, lsmu, muf, out_mu);
  combine_div<<<2048, 256, 0, stream>>>(lvacc, lslv, lvf, out_lv);

  logits_f32<<<128, 256, 0, stream>>>(muf, lvf, d_in[ieps], d_in[iWc], d_in[ibc], out_logits, mode);
}

// Round 3
// 955.880 us; speedup vs baseline: 2.1788x; 1.0622x over previous
//
#include <hip/hip_runtime.h>

typedef unsigned short u16;
typedef __attribute__((ext_vector_type(8))) short short8;
typedef __attribute__((ext_vector_type(4))) float f32x4;

#define NROW 8192

__device__ __forceinline__ float bf2f(u16 h) {
  unsigned u = ((unsigned)h) << 16;
  return __builtin_bit_cast(float, u);
}
// mode-aware load: f32 ? fp32 storage : bf16 storage (upcast)
__device__ __forceinline__ float ldf(const void* p, size_t i, int f32) {
  return f32 ? ((const float*)p)[i] : bf2f(((const u16*)p)[i]);
}
// fp32 -> bf16 round-to-nearest-even
__device__ __forceinline__ u16 f2bf(float f) {
  unsigned b = __builtin_bit_cast(unsigned, f);
  b += 0x7FFFu + ((b >> 16) & 1u);
  return (u16)(b >> 16);
}
// order-preserving float->uint key for atomicMax
__device__ __forceinline__ unsigned fkey(float f) {
  unsigned b = __builtin_bit_cast(unsigned, f);
  return (b & 0x80000000u) ? ~b : (b | 0x80000000u);
}
__device__ __forceinline__ float fkeydec(unsigned k) {
  unsigned b = (k & 0x80000000u) ? (k & 0x7FFFFFFFu) : ~k;
  return __builtin_bit_cast(float, b);
}

// ---- storage-dtype detection on x (N(0,1)).
__global__ void detect3(const u16* __restrict__ xr, unsigned* __restrict__ mode) {
  __shared__ int zc, bg;
  int t = threadIdx.x;   // 256
  if (t == 0) { zc = 0; bg = 0; }
  __syncthreads();
  int zeros_even = 0; int big = 0;
  for (int i = t; i < 4096; i += 256) {
    u16 v = xr[i];
    if (!(i & 1) && v == 0) zeros_even++;
    if (fabsf(bf2f(v)) > 1e6f) big = 1;
  }
  atomicAdd(&zc, zeros_even);
  if (big) atomicOr(&bg, 1);
  __syncthreads();
  if (t == 0) *mode = (zc > 512 || bg) ? 1u : 0u;   // 1 = fp32 storage
}

// ---- adj storage detection (u32 pair pattern 0x00003F80 unique to bf16).
__global__ void detect_adj(const unsigned* __restrict__ a, unsigned* __restrict__ amode) {
  __shared__ int clo;
  int t = threadIdx.x;   // 256
  if (t == 0) clo = 0;
  __syncthreads();
  int c = 0;
  for (int i = t; i < 4096; i += 256)
    if (a[i] == 0x00003F80u) c++;
  atomicAdd(&clo, c);
  __syncthreads();
  if (t == 0) *amode = (clo > 32) ? 1u : 0u;   // 1 = bf16 storage
}

// ---- raw adjacency octet (8 elements), load/decode split for prefetching
struct AdjRaw { int4 w0, w1; };
__device__ __forceinline__ AdjRaw adj_load(const void* adj, size_t base, int amode) {
  AdjRaw r;
  if (amode == 0) {          // u32 per element: 32B
    const int4* p = (const int4*)((const int*)adj + base);
    r.w0 = p[0]; r.w1 = p[1];
  } else {                   // u16 per element: 16B
    r.w0 = *(const int4*)((const u16*)adj + base);
    r.w1 = make_int4(0, 0, 0, 0);
  }
  return r;
}
__device__ __forceinline__ void adj_decode(const AdjRaw& r, int amode, int* aa) {
  if (amode == 0) {
    aa[0] = r.w0.x != 0; aa[1] = r.w0.y != 0; aa[2] = r.w0.z != 0; aa[3] = r.w0.w != 0;
    aa[4] = r.w1.x != 0; aa[5] = r.w1.y != 0; aa[6] = r.w1.z != 0; aa[7] = r.w1.w != 0;
  } else {
    aa[0] = (r.w0.x & 0xFFFF) != 0; aa[1] = ((unsigned)r.w0.x >> 16) != 0;
    aa[2] = (r.w0.y & 0xFFFF) != 0; aa[3] = ((unsigned)r.w0.y >> 16) != 0;
    aa[4] = (r.w0.z & 0xFFFF) != 0; aa[5] = ((unsigned)r.w0.z >> 16) != 0;
    aa[6] = (r.w0.w & 0xFFFF) != 0; aa[7] = ((unsigned)r.w0.w >> 16) != 0;
  }
}

// C[M x N] fp32 = Abf[M x K] @ BT[N x K]^T, all bf16 operands, MFMA, no LDS.
// grid (N/64, M/64), 256 threads; wave w owns rows w*16..+15, 4 n-tiles.
__global__ __launch_bounds__(256) void gemm_mfma(const u16* __restrict__ Abf,
    const u16* __restrict__ BT, float* __restrict__ C, int K, int N) {
  int tid = threadIdx.x;
  int l = tid & 63, w = tid >> 6;
  int m0 = blockIdx.y * 64, n0 = blockIdx.x * 64;
  const u16* arow = Abf + (size_t)(m0 + w * 16 + (l & 15)) * K + (l >> 4) * 8;
  const u16* brow = BT + (size_t)(n0 + (l & 15)) * K + (l >> 4) * 8;
  f32x4 acc[4];
#pragma unroll
  for (int nt = 0; nt < 4; ++nt) acc[nt] = (f32x4){0.f, 0.f, 0.f, 0.f};
  for (int k0 = 0; k0 < K; k0 += 32) {
    short8 a = *(const short8*)(arow + k0);
#pragma unroll
    for (int nt = 0; nt < 4; ++nt) {
      short8 b = *(const short8*)(brow + (size_t)nt * 16 * K + k0);
      acc[nt] = __builtin_amdgcn_mfma_f32_16x16x32_bf16(a, b, acc[nt], 0, 0, 0);
    }
  }
  // C/D layout: col = lane&15, row = (lane>>4)*4 + q
#pragma unroll
  for (int nt = 0; nt < 4; ++nt)
#pragma unroll
    for (int q = 0; q < 4; ++q)
      C[(size_t)(m0 + w * 16 + (l >> 4) * 4 + q) * N + n0 + nt * 16 + (l & 15)] =
          acc[nt][q];
}

// Layer-2/3 dual GEMM: C{0,1}[8192 x 64] fp32 = hbf[8192 x 256] @ BT{0,1}[64 x 256]^T.
// grid (2, 128): blockIdx.x selects matrix; 256 blocks fill the GPU.
__global__ __launch_bounds__(256) void gemm2_dual(const u16* __restrict__ Abf,
    const u16* __restrict__ BT0, const u16* __restrict__ BT1,
    float* __restrict__ C0, float* __restrict__ C1) {
  const int K = 256, N = 64;
  const u16* BT = blockIdx.x ? BT1 : BT0;
  float* C = blockIdx.x ? C1 : C0;
  int tid = threadIdx.x, l = tid & 63, w = tid >> 6;
  int m0 = blockIdx.y * 64;
  const u16* arow = Abf + (size_t)(m0 + w * 16 + (l & 15)) * K + (l >> 4) * 8;
  const u16* brow = BT + (size_t)(l & 15) * K + (l >> 4) * 8;
  f32x4 acc[4];
#pragma unroll
  for (int nt = 0; nt < 4; ++nt) acc[nt] = (f32x4){0.f, 0.f, 0.f, 0.f};
  for (int k0 = 0; k0 < K; k0 += 32) {
    short8 a = *(const short8*)(arow + k0);
#pragma unroll
    for (int nt = 0; nt < 4; ++nt) {
      short8 b = *(const short8*)(brow + (size_t)nt * 16 * K + k0);
      acc[nt] = __builtin_amdgcn_mfma_f32_16x16x32_bf16(a, b, acc[nt], 0, 0, 0);
    }
  }
#pragma unroll
  for (int nt = 0; nt < 4; ++nt)
#pragma unroll
    for (int q = 0; q < 4; ++q)
      C[(size_t)(m0 + w * 16 + (l >> 4) * 4 + q) * N + nt * 16 + (l & 15)] = acc[nt][q];
}

// bf16 copy of a mode-aware buffer (8 elems/thread). n8 = elems/8.
__global__ __launch_bounds__(256) void convert_bf16(const void* __restrict__ in,
    u16* __restrict__ out, int n8, const unsigned* __restrict__ modep) {
  int f32 = (int)*modep;
  int i = blockIdx.x * 256 + threadIdx.x;
  if (i >= n8) return;
  if (f32) {
    float4 v0 = ((const float4*)in)[(size_t)i * 2];
    float4 v1 = ((const float4*)in)[(size_t)i * 2 + 1];
    ushort4 o0 = {f2bf(v0.x), f2bf(v0.y), f2bf(v0.z), f2bf(v0.w)};
    ushort4 o1 = {f2bf(v1.x), f2bf(v1.y), f2bf(v1.z), f2bf(v1.w)};
    ((ushort4*)out)[(size_t)i * 2] = o0;
    ((ushort4*)out)[(size_t)i * 2 + 1] = o1;
  } else {
    ((int4*)out)[i] = ((const int4*)in)[i];   // already bf16: raw copy
  }
}

// transpose + bf16 convert: in fp32 [M][F] -> out bf16 [F][M]. grid (M/32, F/32).
__global__ __launch_bounds__(256) void transpose_bf16(const float* __restrict__ in,
    u16* __restrict__ out, int M, int F) {
  __shared__ float t[32][33];
  int m0 = blockIdx.x * 32, f0 = blockIdx.y * 32;
  int c = threadIdx.x & 31, r = threadIdx.x >> 5;   // r = 0..7
  for (int rr = r; rr < 32; rr += 8)
    t[rr][c] = in[(size_t)(m0 + rr) * F + f0 + c];
  __syncthreads();
  for (int rr = r; rr < 32; rr += 8)
    out[(size_t)(f0 + rr) * M + m0 + c] = f2bf(t[c][rr]);
}

// dual fp32->bf16 transpose (whmu/whlv -> whmuT/whlvT). grid (M/32, F/32, 2).
__global__ __launch_bounds__(256) void transpose_pair(const float* __restrict__ in0,
    const float* __restrict__ in1, u16* __restrict__ out0, u16* __restrict__ out1,
    int M, int F) {
  const float* in = blockIdx.z ? in1 : in0;
  u16* out = blockIdx.z ? out1 : out0;
  __shared__ float t[32][33];
  int m0 = blockIdx.x * 32, f0 = blockIdx.y * 32;
  int c = threadIdx.x & 31, r = threadIdx.x >> 5;
  for (int rr = r; rr < 32; rr += 8)
    t[rr][c] = in[(size_t)(m0 + rr) * F + f0 + c];
  __syncthreads();
  for (int rr = r; rr < 32; rr += 8)
    out[(size_t)(f0 + rr) * M + m0 + c] = f2bf(t[c][rr]);
}

// transpose + bf16 convert from a RAW (mode-aware) buffer. grid (M/32, F/32).
__global__ __launch_bounds__(256) void transpose_any(const void* __restrict__ in,
    u16* __restrict__ out, int M, int F, const unsigned* __restrict__ modep) {
  int f32 = (int)*modep;
  __shared__ u16 t[32][33];
  int m0 = blockIdx.x * 32, f0 = blockIdx.y * 32;
  int c = threadIdx.x & 31, r = threadIdx.x >> 5;
  for (int rr = r; rr < 32; rr += 8)
    t[rr][c] = f2bf(ldf(in, (size_t)(m0 + rr) * F + f0 + c, f32));
  __syncthreads();
  for (int rr = r; rr < 32; rr += 8)
    out[(size_t)(f0 + rr) * M + m0 + c] = t[c][rr];
}

// dual raw transpose (Wmu/Wlv -> WmuT/WlvT). grid (M/32, F/32, 2).
__global__ __launch_bounds__(256) void transpose_w2(const void* __restrict__ in0,
    const void* __restrict__ in1, u16* __restrict__ out0, u16* __restrict__ out1,
    int M, int F, const unsigned* __restrict__ modep) {
  int f32 = (int)*modep;
  const void* in = blockIdx.z ? in1 : in0;
  u16* out = blockIdx.z ? out1 : out0;
  __shared__ u16 t[32][33];
  int m0 = blockIdx.x * 32, f0 = blockIdx.y * 32;
  int c = threadIdx.x & 31, r = threadIdx.x >> 5;
  for (int rr = r; rr < 32; rr += 8)
    t[rr][c] = f2bf(ldf(in, (size_t)(m0 + rr) * F + f0 + c, f32));
  __syncthreads();
  for (int rr = r; rr < 32; rr += 8)
    out[(size_t)(f0 + rr) * M + m0 + c] = t[c][rr];
}

// s_i = Wh_i . a[:F], d_i = Wh_i . a[F:] (Wh fp32, a raw), + global Dmax.
__global__ __launch_bounds__(256) void sd_f32(const float* __restrict__ Wh,
    const void* __restrict__ a2, float* __restrict__ s, float* __restrict__ d,
    unsigned* __restrict__ cell, int F, const unsigned* __restrict__ modep) {
  int f32 = (int)*modep;
  int row = blockIdx.x * 4 + (threadIdx.x >> 6);
  int l = threadIdx.x & 63;
  float ss = 0.f, dd = 0.f;
  for (int k = l; k < F; k += 64) {
    float wv = Wh[(size_t)row * F + k];
    ss += wv * ldf(a2, k, f32);
    dd += wv * ldf(a2, F + k, f32);
  }
#pragma unroll
  for (int off = 32; off > 0; off >>= 1) {
    ss += __shfl_down(ss, off, 64);
    dd += __shfl_down(dd, off, 64);
  }
  if (l == 0) {
    s[row] = ss; d[row] = dd;
    atomicMax(cell, fkey(dd));
  }
}

// dual s/d for layers 2/3 (F = 64). grid (2048, 2).
__global__ __launch_bounds__(256) void sd_dual(const float* __restrict__ Wh0,
    const float* __restrict__ Wh1, const void* __restrict__ a0,
    const void* __restrict__ a1, float* __restrict__ s0, float* __restrict__ s1,
    float* __restrict__ d0, float* __restrict__ d1, unsigned* __restrict__ cells,
    const unsigned* __restrict__ modep) {
  int f32 = (int)*modep;
  int L = blockIdx.y;
  const float* Wh = L ? Wh1 : Wh0;
  const void* a2 = L ? a1 : a0;
  int row = blockIdx.x * 4 + (threadIdx.x >> 6);
  int l = threadIdx.x & 63;
  float wv = Wh[(size_t)row * 64 + l];
  float ss = wv * ldf(a2, l, f32);
  float dd = wv * ldf(a2, 64 + l, f32);
#pragma unroll
  for (int off = 32; off > 0; off >>= 1) {
    ss += __shfl_down(ss, off, 64);
    dd += __shfl_down(dd, off, 64);
  }
  if (l == 0) {
    (L ? s1 : s0)[row] = ss; (L ? d1 : d0)[row] = dd;
    atomicMax(cells + L, fkey(dd));
  }
}

// swizzled P-fragment LDS byte offset: [L][s][mh][row 0..15][kg 0..3] x 8 bf16
__device__ __forceinline__ int pa_off(int L, int s, int mh, int row, int kg) {
  return ((L * 4 + s * 2 + mh) << 10) + (row << 6) + ((kg ^ ((row >> 1) & 3)) << 4);
}

// Flash GAT layer(s) on MFMA. R=32 rows/block, 64-j tile per iteration.
// SINGLE barrier per iteration: PA double-buffered; score(t+1) overlaps the
// MFMA cluster of PV(t) (separate pipes). adj prefetched 1 iter ahead (reg).
// Block swizzle: consecutive blockIdx -> consecutive rblk (same js), so all
// js-siblings of a row-block land on the same XCD (atomics + s/d L2-local).
template <int NL, int FDIM, int JS>
__global__ __launch_bounds__(256) void flash_mfma(
    const u16* __restrict__ whTa, const u16* __restrict__ whTb,   // bf16 [FDIM][NROW]
    const float* __restrict__ sa, const float* __restrict__ da,
    const float* __restrict__ sb, const float* __restrict__ db,
    const unsigned* __restrict__ cella, const unsigned* __restrict__ cellb,
    const void* __restrict__ adj, const unsigned* __restrict__ amodep,
    float* __restrict__ acca, float* __restrict__ lsa,
    float* __restrict__ accb, float* __restrict__ lsb) {
  constexpr int JLEN = NROW / JS;
  constexpr int NIT = JLEN / 64;
  constexpr int NTW = (NL == 1) ? 4 : 2;     // n-tiles per wave
  constexpr int NRBLK = NROW / 32;
  __shared__ __align__(16) char PA[2][NL * 4096];   // double-buffered P frags
  __shared__ float ddl[2][NL][64];                  // d_j double-buffer
  __shared__ float sv_[NL][32], Ms_[NL][32];
  int tid = threadIdx.x;
  int amode = (int)*amodep;
  int rblk = blockIdx.x % NRBLK, js = blockIdx.x / NRBLK;
  int r0 = rblk * 32;
  size_t jbase = (size_t)js * JLEN;
  if (tid < 32 * NL) {
    int L = tid >> 5, i = tid & 31;
    float Dm = fkeydec(L ? *cellb : *cella);
    float t0 = (L ? sb : sa)[r0 + i];
    sv_[L][i] = t0;
    float m = t0 + Dm;
    Ms_[L][i] = fmaxf(m, 0.2f * m);   // lrelu(s_i + Dmax) >= all e[i,:]
  }
  if (tid < 64 * NL) {
    int L = tid >> 6, i = tid & 63;
    ddl[0][L][i] = (L ? db : da)[jbase + i];
  }
  __syncthreads();
  // score-phase mapping: 32 rows x 8 j-octets
  int sr = tid >> 3, sjo = tid & 7;
  int s_w = sjo >> 2, kg_w = sjo & 3, mh_w = sr >> 4, row_w = sr & 15;
  // PV-phase mapping
  int l = tid & 63, w = tid >> 6;
  int layer = (NL == 1) ? 0 : (w >> 1);
  int ntb = (NL == 1) ? (w * 4) : ((w & 1) * 2);
  const u16* whT = layer ? whTb : whTa;
  f32x4 acc[2][NTW];
#pragma unroll
  for (int m = 0; m < 2; ++m)
#pragma unroll
    for (int n = 0; n < NTW; ++n) acc[m][n] = (f32x4){0.f, 0.f, 0.f, 0.f};
  float psum[NL];
#pragma unroll
  for (int L = 0; L < NL; ++L) psum[L] = 0.f;
  size_t abase = (size_t)(r0 + sr) * NROW + jbase + sjo * 8;

  AdjRaw araw = adj_load(adj, abase, amode);          // it = 0
  for (int it = 0; it < NIT; ++it) {
    size_t j0 = jbase + (size_t)it * 64;
    int cur = it & 1;
    // prefetch next tile's d_j (writes the buffer last read at it-1; safe:
    // all waves passed barrier B_{it-1} after score_{it-1} finished reading)
    if (it + 1 < NIT && tid < 64 * NL) {
      int L = tid >> 6, i = tid & 63;
      ddl[cur ^ 1][L][i] = (L ? db : da)[j0 + 64 + i];
    }
    // B fragments for this tile (L2-mostly; issue before score)
    short8 bfr[2][NTW];
#pragma unroll
    for (int s2 = 0; s2 < 2; ++s2) {
      size_t jcol = j0 + s2 * 32 + (size_t)(l >> 4) * 8;
#pragma unroll
      for (int nt = 0; nt < NTW; ++nt)
        bfr[s2][nt] =
            *(const short8*)&whT[(size_t)((ntb + nt) * 16 + (l & 15)) * NROW + jcol];
    }
    // prefetch next iteration's adjacency (HBM latency spans the barrier)
    AdjRaw anext = araw;
    if (it + 1 < NIT) anext = adj_load(adj, abase + (size_t)(it + 1) * 64, amode);
    int aa[8];
    adj_decode(araw, amode, aa);
    // ---- score phase: P[r, j0+sjo*8 .. +7] in bf16 into PA[cur]
    char* pab = PA[cur];
#pragma unroll
    for (int L = 0; L < NL; ++L) {
      float sv = sv_[L][sr], Mr = Ms_[L][sr];
      short8 pk;
      float ps = 0.f;
#pragma unroll
      for (int q = 0; q < 8; ++q) {
        float t = sv + ddl[cur][L][sjo * 8 + q];
        float e = fmaxf(t, 0.2f * t) - Mr;           // <= 0
        float p = aa[q] ? __expf(e) : 0.f;
        ps += p;
        pk[q] = (short)f2bf(p);
      }
      psum[L] += ps;
      *(short8*)(pab + pa_off(L, s_w, mh_w, row_w, kg_w)) = pk;
    }
    __syncthreads();                  // PA[cur] ready (ONLY barrier this iter)
    // ---- PV phase: out[r0..+32, wave n-range] += P * WhT^T  (MFMA)
    __builtin_amdgcn_s_setprio(1);
#pragma unroll
    for (int s2 = 0; s2 < 2; ++s2) {
      short8 a0 = *(const short8*)(pab + pa_off(layer, s2, 0, l & 15, l >> 4));
      short8 a1 = *(const short8*)(pab + pa_off(layer, s2, 1, l & 15, l >> 4));
#pragma unroll
      for (int nt = 0; nt < NTW; ++nt) {
        acc[0][nt] = __builtin_amdgcn_mfma_f32_16x16x32_bf16(a0, bfr[s2][nt],
                                                             acc[0][nt], 0, 0, 0);
        acc[1][nt] = __builtin_amdgcn_mfma_f32_16x16x32_bf16(a1, bfr[s2][nt],
                                                             acc[1][nt], 0, 0, 0);
      }
    }
    __builtin_amdgcn_s_setprio(0);
    // no second barrier: next score writes PA[cur^1], whose previous readers
    // (PV at it-1) completed before this iteration's barrier.
    araw = anext;
  }
  // ---- lsum: per-thread psum -> LDS (reuse PA) -> one atomic per row
  __syncthreads();                    // last PV reads of PA done
  float* red = (float*)PA;
#pragma unroll
  for (int L = 0; L < NL; ++L) red[L * 256 + sr * 8 + sjo] = psum[L];
  __syncthreads();
  if (tid < 32 * NL) {
    int L = tid >> 5, r = tid & 31;
    float t = 0.f;
#pragma unroll
    for (int q = 0; q < 8; ++q) t += red[L * 256 + r * 8 + q];
    atomicAdd(&(L ? lsb : lsa)[r0 + r], t);
  }
  // ---- accumulator flush (C/D layout: col=lane&15, row=(lane>>4)*4+reg)
  float* accp = layer ? accb : acca;
#pragma unroll
  for (int m = 0; m < 2; ++m)
#pragma unroll
    for (int nt = 0; nt < NTW; ++nt)
#pragma unroll
      for (int q = 0; q < 4; ++q)
        atomicAdd(&accp[(size_t)(r0 + m * 16 + (l >> 4) * 4 + q) * FDIM +
                        (ntb + nt) * 16 + (l & 15)],
                  acc[m][nt][q]);
}

// hbf = bf16(elu(acc/lsum)) (layer 1). n = 8192*256. fp32 h is dropped.
__global__ __launch_bounds__(256) void combine_elu(const float* __restrict__ acc_g,
    const float* __restrict__ lsum_g, u16* __restrict__ hbf) {
  int idx = blockIdx.x * 256 + threadIdx.x;
  float x = acc_g[idx] / lsum_g[idx >> 8];
  x = (x > 0.f) ? x : (__expf(x) - 1.f);
  hbf[idx] = f2bf(x);
}

// out = acc/lsum fp32, dual store (ws buffer + d_out region). n = 8192*64.
__global__ __launch_bounds__(256) void combine_div(const float* __restrict__ acc_g,
    const float* __restrict__ lsum_g, float* __restrict__ outf, float* __restrict__ outd) {
  int idx = blockIdx.x * 256 + threadIdx.x;
  float x = acc_g[idx] / lsum_g[idx >> 6];
  outf[idx] = x;
  outd[idx] = x;
}

// logits = (mu + eps*exp(0.5*logvar)) @ Wc + bc (mu/lv fp32, rest raw). fp32 out.
__global__ __launch_bounds__(256) void logits_f32(const float* __restrict__ mu,
    const float* __restrict__ lv, const void* __restrict__ eps,
    const void* __restrict__ Wc, const void* __restrict__ bcv,
    float* __restrict__ outL, const unsigned* __restrict__ modep) {
  int f32 = (int)*modep;
  __shared__ float zs[64 * 64];
  __shared__ float wcs[64 * 16];
  int tid = threadIdx.x;
  for (int i = tid; i < 1024; i += 256) wcs[i] = ldf(Wc, i, f32);
  int rl = tid >> 2, cs = (tid & 3) * 16;
  int row = blockIdx.x * 64 + rl;
  size_t rb64 = (size_t)row * 64;
  for (int c = cs; c < cs + 16; ++c)
    zs[rl * 64 + c] = mu[rb64 + c] + ldf(eps, rb64 + c, f32) * __expf(0.5f * lv[rb64 + c]);
  __syncthreads();
  for (int it = tid; it < 1024; it += 256) {
    int r = it >> 4, oc = it & 15;
    float a = ldf(bcv, oc, f32);
    for (int c = 0; c < 64; ++c) a += zs[r * 64 + c] * wcs[c * 16 + oc];
    outL[(size_t)(blockIdx.x * 64 + r) * 16 + oc] = a;
  }
}

extern "C" void kernel_launch(void* const* d_in, const int* in_sizes, int n_in,
                              void* d_out, int out_size, void* d_ws, size_t ws_size,
                              hipStream_t stream) {
  (void)out_size; (void)ws_size;
  // ---- size-based input resolution (robust to permutation; ties in dict order)
  int ix = 0, iadj = 1, ieps = 2, iW1 = 3, ia1 = 4, iWmu = 5, iamu = 6,
      iWlv = 7, ialv = 8, iWc = 9, ibc = 10;
  {
    int fmu = -1, flv = -1, fam = -1, fal = -1;
    for (int i = 0; i < n_in; ++i) {
      switch (in_sizes[i]) {
        case 67108864: iadj = i; break;
        case 4194304:  ix   = i; break;
        case 524288:   ieps = i; break;
        case 131072:   iW1  = i; break;
        case 512:      ia1  = i; break;
        case 1024:     iWc  = i; break;
        case 16:       ibc  = i; break;
        case 16384:    if (fmu < 0) fmu = i; else flv = i; break;
        case 128:      if (fam < 0) fam = i; else fal = i; break;
        default: break;
      }
    }
    if (fmu >= 0 && flv >= 0) { iWmu = fmu; iWlv = flv; }
    if (fam >= 0 && fal >= 0) { iamu = fam; ialv = fal; }
  }
  const void* adj = d_in[iadj];
  char* ws = (char*)d_ws;
  const size_t KB = 1024, MB = 1024 * 1024;
  // ---- workspace (<= 24.6 MB) ----
  float* wh1   = (float*)(ws + 0);                 // 8MB [dead after sd1/transpose1]
  float* whmu  = (float*)(ws + 0);                 // 2MB [overlay]
  float* whlv  = (float*)(ws + 2 * MB);            // 2MB [overlay]
  float* muf   = (float*)(ws + 4 * MB);            // 2MB [overlay]
  float* lvf   = (float*)(ws + 6 * MB);            // 2MB [overlay]
  u16*   xbf   = (u16*)(ws + 8 * MB);              // 8MB bf16 x [dead after gemm1]
  u16*   whT1  = (u16*)(ws + 8 * MB);              // 4MB bf16 [256][8192] [overlay]
  u16*   hbf   = (u16*)(ws + 12 * MB);             // 4MB bf16 [8192][256]
  float* hacc  = (float*)(ws + 16 * MB);           // 8MB [dead after combine1]
  float* macc  = (float*)(ws + 16 * MB);           // 2MB [overlay, memset mid-stream]
  float* lvacc = (float*)(ws + 18 * MB);           // 2MB [overlay, memset mid-stream]
  u16*   whmuT = (u16*)(ws + 20 * MB);             // 1MB bf16 [64][8192]
  u16*   whlvT = (u16*)(ws + 21 * MB);             // 1MB bf16 [64][8192]
  u16*   W1T   = (u16*)(ws + 22 * MB);             // 256KB bf16 [256][512]
  u16*   WmuT  = (u16*)(ws + 22 * MB + 256 * KB);  // 32KB bf16 [64][256]
  u16*   WlvT  = (u16*)(ws + 22 * MB + 288 * KB);  // 32KB bf16 [64][256]
  float* lsum1 = (float*)(ws + 24 * MB);           // 32KB
  float* lsmu  = (float*)(ws + 24 * MB + 32 * KB);
  float* lslv  = (float*)(ws + 24 * MB + 64 * KB);
  float* s1    = (float*)(ws + 24 * MB + 96 * KB);
  float* d1    = (float*)(ws + 24 * MB + 128 * KB);
  float* smu   = (float*)(ws + 24 * MB + 160 * KB);
  float* dmu   = (float*)(ws + 24 * MB + 192 * KB);
  float* slv   = (float*)(ws + 24 * MB + 224 * KB);
  float* dlv   = (float*)(ws + 24 * MB + 256 * KB);
  unsigned* dmx   = (unsigned*)(ws + 24 * MB + 288 * KB);  // 4 cells
  unsigned* mode  = (unsigned*)(ws + 24 * MB + 289 * KB);
  unsigned* amode = (unsigned*)(ws + 24 * MB + 290 * KB);

  // fp32 output layout: [logits 8192*16 | mu 8192*64 | logvar 8192*64]
  float* out_logits = (float*)d_out;
  float* out_mu     = (float*)d_out + 131072;
  float* out_lv     = (float*)d_out + 655360;

  (void)hipMemsetAsync(dmx, 0, 16, stream);
  (void)hipMemsetAsync(lsum1, 0, 96 * KB, stream);        // lsum1+lsmu+lslv
  (void)hipMemsetAsync(hacc, 0, 8 * MB, stream);
  detect3<<<1, 256, 0, stream>>>((const u16*)d_in[ix], mode);
  detect_adj<<<1, 256, 0, stream>>>((const unsigned*)adj, amode);

  // layer 1: xbf/W1T bf16, Wh1 = xbf @ W1T^T (MFMA), WhT1 bf16, s/d,
  // MFMA flash (JS=8, 2048 blocks, 1 barrier/iter), combine+elu -> hbf
  convert_bf16<<<2048, 256, 0, stream>>>(d_in[ix], xbf, 524288, mode);
  transpose_any<<<dim3(16, 8), 256, 0, stream>>>(d_in[iW1], W1T, 512, 256, mode);
  gemm_mfma<<<dim3(4, 128), 256, 0, stream>>>(xbf, W1T, wh1, 512, 256);
  transpose_bf16<<<dim3(256, 8), 256, 0, stream>>>(wh1, whT1, 8192, 256);
  sd_f32<<<2048, 256, 0, stream>>>(wh1, d_in[ia1], s1, d1, dmx + 0, 256, mode);
  flash_mfma<1, 256, 8><<<2048, 256, 0, stream>>>(whT1, nullptr, s1, d1,
      nullptr, nullptr, dmx + 0, nullptr, adj, amode, hacc, lsum1, nullptr, nullptr);
  combine_elu<<<8192, 256, 0, stream>>>(hacc, lsum1, hbf);

  // zero layer-2/3 accumulators (overlaying dead hacc; stream-ordered)
  (void)hipMemsetAsync(macc, 0, 4 * MB, stream);          // macc + lvacc

  // layers 2/3: dual MFMA GEMM from hbf, dual transposes, dual s/d, FUSED flash
  transpose_w2<<<dim3(8, 2, 2), 256, 0, stream>>>(d_in[iWmu], d_in[iWlv],
      WmuT, WlvT, 256, 64, mode);
  gemm2_dual<<<dim3(2, 128), 256, 0, stream>>>(hbf, WmuT, WlvT, whmu, whlv);
  transpose_pair<<<dim3(256, 2, 2), 256, 0, stream>>>(whmu, whlv, whmuT, whlvT,
      8192, 64);
  sd_dual<<<dim3(2048, 2), 256, 0, stream>>>(whmu, whlv, d_in[iamu], d_in[ialv],
      smu, slv, dmu, dlv, dmx + 1, mode);
  flash_mfma<2, 64, 8><<<2048, 256, 0, stream>>>(whmuT, whlvT, smu, dmu, slv, dlv,
      dmx + 1, dmx + 2, adj, amode, macc, lsmu, lvacc, lslv);
  combine_div<<<2048, 256, 0, stream>>>(macc, lsmu, muf, out_mu);
  combine_div<<<2048, 256, 0, stream>>>(lvacc, lslv, lvf, out_lv);

  logits_f32<<<128, 256, 0, stream>>>(muf, lvf, d_in[ieps], d_in[iWc], d_in[ibc], out_logits, mode);
}

// Round 4
// 690.090 us; speedup vs baseline: 3.0180x; 1.3852x over previous
//
#include <hip/hip_runtime.h>

typedef unsigned short u16;
typedef __attribute__((ext_vector_type(8))) short short8;
typedef __attribute__((ext_vector_type(4))) float f32x4;

#define NROW 8192

__device__ __forceinline__ float bf2f(u16 h) {
  unsigned u = ((unsigned)h) << 16;
  return __builtin_bit_cast(float, u);
}
// mode-aware load: f32 ? fp32 storage : bf16 storage (upcast)
__device__ __forceinline__ float ldf(const void* p, size_t i, int f32) {
  return f32 ? ((const float*)p)[i] : bf2f(((const u16*)p)[i]);
}
// fp32 -> bf16 round-to-nearest-even
__device__ __forceinline__ u16 f2bf(float f) {
  unsigned b = __builtin_bit_cast(unsigned, f);
  b += 0x7FFFu + ((b >> 16) & 1u);
  return (u16)(b >> 16);
}

// ---- storage-dtype detection on x (N(0,1)).
__global__ void detect3(const u16* __restrict__ xr, unsigned* __restrict__ mode) {
  __shared__ int zc, bg;
  int t = threadIdx.x;   // 256
  if (t == 0) { zc = 0; bg = 0; }
  __syncthreads();
  int zeros_even = 0; int big = 0;
  for (int i = t; i < 4096; i += 256) {
    u16 v = xr[i];
    if (!(i & 1) && v == 0) zeros_even++;
    if (fabsf(bf2f(v)) > 1e6f) big = 1;
  }
  atomicAdd(&zc, zeros_even);
  if (big) atomicOr(&bg, 1);
  __syncthreads();
  if (t == 0) *mode = (zc > 512 || bg) ? 1u : 0u;   // 1 = fp32 storage
}

// ---- adj storage detection (u32 pair pattern 0x00003F80 unique to bf16).
__global__ void detect_adj(const unsigned* __restrict__ a, unsigned* __restrict__ amode) {
  __shared__ int clo;
  int t = threadIdx.x;   // 256
  if (t == 0) clo = 0;
  __syncthreads();
  int c = 0;
  for (int i = t; i < 4096; i += 256)
    if (a[i] == 0x00003F80u) c++;
  atomicAdd(&clo, c);
  __syncthreads();
  if (t == 0) *amode = (clo > 32) ? 1u : 0u;   // 1 = bf16 storage
}

// ---- raw adjacency octet (8 elements), load/decode split for prefetching
struct AdjRaw { int4 w0, w1; };
__device__ __forceinline__ AdjRaw adj_load(const void* adj, size_t base, int amode) {
  AdjRaw r;
  if (amode == 0) {          // u32 per element: 32B
    const int4* p = (const int4*)((const int*)adj + base);
    r.w0 = p[0]; r.w1 = p[1];
  } else {                   // u16 per element: 16B
    r.w0 = *(const int4*)((const u16*)adj + base);
    r.w1 = make_int4(0, 0, 0, 0);
  }
  return r;
}
__device__ __forceinline__ void adj_decode(const AdjRaw& r, int amode, int* aa) {
  if (amode == 0) {
    aa[0] = r.w0.x != 0; aa[1] = r.w0.y != 0; aa[2] = r.w0.z != 0; aa[3] = r.w0.w != 0;
    aa[4] = r.w1.x != 0; aa[5] = r.w1.y != 0; aa[6] = r.w1.z != 0; aa[7] = r.w1.w != 0;
  } else {
    aa[0] = (r.w0.x & 0xFFFF) != 0; aa[1] = ((unsigned)r.w0.x >> 16) != 0;
    aa[2] = (r.w0.y & 0xFFFF) != 0; aa[3] = ((unsigned)r.w0.y >> 16) != 0;
    aa[4] = (r.w0.z & 0xFFFF) != 0; aa[5] = ((unsigned)r.w0.z >> 16) != 0;
    aa[6] = (r.w0.w & 0xFFFF) != 0; aa[7] = ((unsigned)r.w0.w >> 16) != 0;
  }
}

// C[M x N] fp32 = Abf[M x K] @ BT[N x K]^T, all bf16 operands, MFMA, no LDS.
// grid (N/64, M/64), 256 threads; wave w owns rows w*16..+15, 4 n-tiles.
__global__ __launch_bounds__(256) void gemm_mfma(const u16* __restrict__ Abf,
    const u16* __restrict__ BT, float* __restrict__ C, int K, int N) {
  int tid = threadIdx.x;
  int l = tid & 63, w = tid >> 6;
  int m0 = blockIdx.y * 64, n0 = blockIdx.x * 64;
  const u16* arow = Abf + (size_t)(m0 + w * 16 + (l & 15)) * K + (l >> 4) * 8;
  const u16* brow = BT + (size_t)(n0 + (l & 15)) * K + (l >> 4) * 8;
  f32x4 acc[4];
#pragma unroll
  for (int nt = 0; nt < 4; ++nt) acc[nt] = (f32x4){0.f, 0.f, 0.f, 0.f};
  for (int k0 = 0; k0 < K; k0 += 32) {
    short8 a = *(const short8*)(arow + k0);
#pragma unroll
    for (int nt = 0; nt < 4; ++nt) {
      short8 b = *(const short8*)(brow + (size_t)nt * 16 * K + k0);
      acc[nt] = __builtin_amdgcn_mfma_f32_16x16x32_bf16(a, b, acc[nt], 0, 0, 0);
    }
  }
  // C/D layout: col = lane&15, row = (lane>>4)*4 + q
#pragma unroll
  for (int nt = 0; nt < 4; ++nt)
#pragma unroll
    for (int q = 0; q < 4; ++q)
      C[(size_t)(m0 + w * 16 + (l >> 4) * 4 + q) * N + n0 + nt * 16 + (l & 15)] =
          acc[nt][q];
}

// Layer-2/3 dual GEMM: C{0,1}[8192 x 64] fp32 = hbf[8192 x 256] @ BT{0,1}[64 x 256]^T.
// grid (2, 128): blockIdx.x selects matrix; 256 blocks fill the GPU.
__global__ __launch_bounds__(256) void gemm2_dual(const u16* __restrict__ Abf,
    const u16* __restrict__ BT0, const u16* __restrict__ BT1,
    float* __restrict__ C0, float* __restrict__ C1) {
  const int K = 256, N = 64;
  const u16* BT = blockIdx.x ? BT1 : BT0;
  float* C = blockIdx.x ? C1 : C0;
  int tid = threadIdx.x, l = tid & 63, w = tid >> 6;
  int m0 = blockIdx.y * 64;
  const u16* arow = Abf + (size_t)(m0 + w * 16 + (l & 15)) * K + (l >> 4) * 8;
  const u16* brow = BT + (size_t)(l & 15) * K + (l >> 4) * 8;
  f32x4 acc[4];
#pragma unroll
  for (int nt = 0; nt < 4; ++nt) acc[nt] = (f32x4){0.f, 0.f, 0.f, 0.f};
  for (int k0 = 0; k0 < K; k0 += 32) {
    short8 a = *(const short8*)(arow + k0);
#pragma unroll
    for (int nt = 0; nt < 4; ++nt) {
      short8 b = *(const short8*)(brow + (size_t)nt * 16 * K + k0);
      acc[nt] = __builtin_amdgcn_mfma_f32_16x16x32_bf16(a, b, acc[nt], 0, 0, 0);
    }
  }
#pragma unroll
  for (int nt = 0; nt < 4; ++nt)
#pragma unroll
    for (int q = 0; q < 4; ++q)
      C[(size_t)(m0 + w * 16 + (l >> 4) * 4 + q) * N + nt * 16 + (l & 15)] = acc[nt][q];
}

// bf16 copy of a mode-aware buffer (8 elems/thread). n8 = elems/8.
__global__ __launch_bounds__(256) void convert_bf16(const void* __restrict__ in,
    u16* __restrict__ out, int n8, const unsigned* __restrict__ modep) {
  int f32 = (int)*modep;
  int i = blockIdx.x * 256 + threadIdx.x;
  if (i >= n8) return;
  if (f32) {
    float4 v0 = ((const float4*)in)[(size_t)i * 2];
    float4 v1 = ((const float4*)in)[(size_t)i * 2 + 1];
    ushort4 o0 = {f2bf(v0.x), f2bf(v0.y), f2bf(v0.z), f2bf(v0.w)};
    ushort4 o1 = {f2bf(v1.x), f2bf(v1.y), f2bf(v1.z), f2bf(v1.w)};
    ((ushort4*)out)[(size_t)i * 2] = o0;
    ((ushort4*)out)[(size_t)i * 2 + 1] = o1;
  } else {
    ((int4*)out)[i] = ((const int4*)in)[i];   // already bf16: raw copy
  }
}

// transpose + bf16 convert: in fp32 [M][F] -> out bf16 [F][M]. grid (M/32, F/32).
__global__ __launch_bounds__(256) void transpose_bf16(const float* __restrict__ in,
    u16* __restrict__ out, int M, int F) {
  __shared__ float t[32][33];
  int m0 = blockIdx.x * 32, f0 = blockIdx.y * 32;
  int c = threadIdx.x & 31, r = threadIdx.x >> 5;   // r = 0..7
  for (int rr = r; rr < 32; rr += 8)
    t[rr][c] = in[(size_t)(m0 + rr) * F + f0 + c];
  __syncthreads();
  for (int rr = r; rr < 32; rr += 8)
    out[(size_t)(f0 + rr) * M + m0 + c] = f2bf(t[c][rr]);
}

// dual fp32->bf16 transpose (whmu/whlv -> whmuT/whlvT). grid (M/32, F/32, 2).
__global__ __launch_bounds__(256) void transpose_pair(const float* __restrict__ in0,
    const float* __restrict__ in1, u16* __restrict__ out0, u16* __restrict__ out1,
    int M, int F) {
  const float* in = blockIdx.z ? in1 : in0;
  u16* out = blockIdx.z ? out1 : out0;
  __shared__ float t[32][33];
  int m0 = blockIdx.x * 32, f0 = blockIdx.y * 32;
  int c = threadIdx.x & 31, r = threadIdx.x >> 5;
  for (int rr = r; rr < 32; rr += 8)
    t[rr][c] = in[(size_t)(m0 + rr) * F + f0 + c];
  __syncthreads();
  for (int rr = r; rr < 32; rr += 8)
    out[(size_t)(f0 + rr) * M + m0 + c] = f2bf(t[c][rr]);
}

// transpose + bf16 convert from a RAW (mode-aware) buffer. grid (M/32, F/32).
__global__ __launch_bounds__(256) void transpose_any(const void* __restrict__ in,
    u16* __restrict__ out, int M, int F, const unsigned* __restrict__ modep) {
  int f32 = (int)*modep;
  __shared__ u16 t[32][33];
  int m0 = blockIdx.x * 32, f0 = blockIdx.y * 32;
  int c = threadIdx.x & 31, r = threadIdx.x >> 5;
  for (int rr = r; rr < 32; rr += 8)
    t[rr][c] = f2bf(ldf(in, (size_t)(m0 + rr) * F + f0 + c, f32));
  __syncthreads();
  for (int rr = r; rr < 32; rr += 8)
    out[(size_t)(f0 + rr) * M + m0 + c] = t[c][rr];
}

// dual raw transpose (Wmu/Wlv -> WmuT/WlvT). grid (M/32, F/32, 2).
__global__ __launch_bounds__(256) void transpose_w2(const void* __restrict__ in0,
    const void* __restrict__ in1, u16* __restrict__ out0, u16* __restrict__ out1,
    int M, int F, const unsigned* __restrict__ modep) {
  int f32 = (int)*modep;
  const void* in = blockIdx.z ? in1 : in0;
  u16* out = blockIdx.z ? out1 : out0;
  __shared__ u16 t[32][33];
  int m0 = blockIdx.x * 32, f0 = blockIdx.y * 32;
  int c = threadIdx.x & 31, r = threadIdx.x >> 5;
  for (int rr = r; rr < 32; rr += 8)
    t[rr][c] = f2bf(ldf(in, (size_t)(m0 + rr) * F + f0 + c, f32));
  __syncthreads();
  for (int rr = r; rr < 32; rr += 8)
    out[(size_t)(f0 + rr) * M + m0 + c] = t[c][rr];
}

// s_i = Wh_i . a[:F], d_i = Wh_i . a[F:] (Wh fp32, a raw). NO atomics.
__global__ __launch_bounds__(256) void sd_f32(const float* __restrict__ Wh,
    const void* __restrict__ a2, float* __restrict__ s, float* __restrict__ d,
    int F, const unsigned* __restrict__ modep) {
  int f32 = (int)*modep;
  int row = blockIdx.x * 4 + (threadIdx.x >> 6);
  int l = threadIdx.x & 63;
  float ss = 0.f, dd = 0.f;
  for (int k = l; k < F; k += 64) {
    float wv = Wh[(size_t)row * F + k];
    ss += wv * ldf(a2, k, f32);
    dd += wv * ldf(a2, F + k, f32);
  }
#pragma unroll
  for (int off = 32; off > 0; off >>= 1) {
    ss += __shfl_down(ss, off, 64);
    dd += __shfl_down(dd, off, 64);
  }
  if (l == 0) { s[row] = ss; d[row] = dd; }
}

// dual s/d for layers 2/3 (F = 64). grid (2048, 2). NO atomics.
__global__ __launch_bounds__(256) void sd_dual(const float* __restrict__ Wh0,
    const float* __restrict__ Wh1, const void* __restrict__ a0,
    const void* __restrict__ a1, float* __restrict__ s0, float* __restrict__ s1,
    float* __restrict__ d0, float* __restrict__ d1,
    const unsigned* __restrict__ modep) {
  int f32 = (int)*modep;
  int L = blockIdx.y;
  const float* Wh = L ? Wh1 : Wh0;
  const void* a2 = L ? a1 : a0;
  int row = blockIdx.x * 4 + (threadIdx.x >> 6);
  int l = threadIdx.x & 63;
  float wv = Wh[(size_t)row * 64 + l];
  float ss = wv * ldf(a2, l, f32);
  float dd = wv * ldf(a2, 64 + l, f32);
#pragma unroll
  for (int off = 32; off > 0; off >>= 1) {
    ss += __shfl_down(ss, off, 64);
    dd += __shfl_down(dd, off, 64);
  }
  if (l == 0) { (L ? s1 : s0)[row] = ss; (L ? d1 : d0)[row] = dd; }
}

// Dmax: single block per array, LDS tree, plain store (no atomics, no
// contention). grid = #arrays; writes cells[blockIdx.x * 16] (64B apart).
__global__ __launch_bounds__(256) void dmax_reduce(const float* __restrict__ da,
    const float* __restrict__ db, float* __restrict__ cells) {
  const float* d = blockIdx.x ? db : da;
  __shared__ float red[256];
  float m = -3.4e38f;
  for (int i = threadIdx.x; i < NROW; i += 256) m = fmaxf(m, d[i]);
  red[threadIdx.x] = m;
  __syncthreads();
#pragma unroll
  for (int sft = 128; sft > 0; sft >>= 1) {
    if (threadIdx.x < sft) red[threadIdx.x] = fmaxf(red[threadIdx.x], red[threadIdx.x + sft]);
    __syncthreads();
  }
  if (threadIdx.x == 0) cells[blockIdx.x * 16] = red[0];
}

// swizzled P-fragment LDS byte offset: [L][s][mh][row 0..15][kg 0..3] x 8 bf16
__device__ __forceinline__ int pa_off(int L, int s, int mh, int row, int kg) {
  return ((L * 4 + s * 2 + mh) << 10) + (row << 6) + ((kg ^ ((row >> 1) & 3)) << 4);
}

// Flash GAT layer(s) on MFMA. R=32 rows/block, 64-j tile per iteration.
// SINGLE barrier per iteration: PA double-buffered; score(t+1) overlaps the
// MFMA cluster of PV(t) (separate pipes). adj prefetched 1 iter ahead (reg).
// Block swizzle: consecutive blockIdx -> consecutive rblk (same js), so all
// js-siblings of a row-block land on the same XCD (atomics + s/d L2-local).
template <int NL, int FDIM, int JS>
__global__ __launch_bounds__(256) void flash_mfma(
    const u16* __restrict__ whTa, const u16* __restrict__ whTb,   // bf16 [FDIM][NROW]
    const float* __restrict__ sa, const float* __restrict__ da,
    const float* __restrict__ sb, const float* __restrict__ db,
    const float* __restrict__ cella, const float* __restrict__ cellb,
    const void* __restrict__ adj, const unsigned* __restrict__ amodep,
    float* __restrict__ acca, float* __restrict__ lsa,
    float* __restrict__ accb, float* __restrict__ lsb) {
  constexpr int JLEN = NROW / JS;
  constexpr int NIT = JLEN / 64;
  constexpr int NTW = (NL == 1) ? 4 : 2;     // n-tiles per wave
  constexpr int NRBLK = NROW / 32;
  __shared__ __align__(16) char PA[2][NL * 4096];   // double-buffered P frags
  __shared__ float ddl[2][NL][64];                  // d_j double-buffer
  __shared__ float sv_[NL][32], Ms_[NL][32];
  int tid = threadIdx.x;
  int amode = (int)*amodep;
  int rblk = blockIdx.x % NRBLK, js = blockIdx.x / NRBLK;
  int r0 = rblk * 32;
  size_t jbase = (size_t)js * JLEN;
  if (tid < 32 * NL) {
    int L = tid >> 5, i = tid & 31;
    float Dm = L ? *cellb : *cella;
    float t0 = (L ? sb : sa)[r0 + i];
    sv_[L][i] = t0;
    float m = t0 + Dm;
    Ms_[L][i] = fmaxf(m, 0.2f * m);   // lrelu(s_i + Dmax) >= all e[i,:]
  }
  if (tid < 64 * NL) {
    int L = tid >> 6, i = tid & 63;
    ddl[0][L][i] = (L ? db : da)[jbase + i];
  }
  __syncthreads();
  // score-phase mapping: 32 rows x 8 j-octets
  int sr = tid >> 3, sjo = tid & 7;
  int s_w = sjo >> 2, kg_w = sjo & 3, mh_w = sr >> 4, row_w = sr & 15;
  // PV-phase mapping
  int l = tid & 63, w = tid >> 6;
  int layer = (NL == 1) ? 0 : (w >> 1);
  int ntb = (NL == 1) ? (w * 4) : ((w & 1) * 2);
  const u16* whT = layer ? whTb : whTa;
  f32x4 acc[2][NTW];
#pragma unroll
  for (int m = 0; m < 2; ++m)
#pragma unroll
    for (int n = 0; n < NTW; ++n) acc[m][n] = (f32x4){0.f, 0.f, 0.f, 0.f};
  float psum[NL];
#pragma unroll
  for (int L = 0; L < NL; ++L) psum[L] = 0.f;
  size_t abase = (size_t)(r0 + sr) * NROW + jbase + sjo * 8;

  AdjRaw araw = adj_load(adj, abase, amode);          // it = 0
  for (int it = 0; it < NIT; ++it) {
    size_t j0 = jbase + (size_t)it * 64;
    int cur = it & 1;
    // prefetch next tile's d_j (writes the buffer last read at it-1; safe:
    // all waves passed barrier B_{it-1} after score_{it-1} finished reading)
    if (it + 1 < NIT && tid < 64 * NL) {
      int L = tid >> 6, i = tid & 63;
      ddl[cur ^ 1][L][i] = (L ? db : da)[j0 + 64 + i];
    }
    // B fragments for this tile (L2-mostly; issue before score)
    short8 bfr[2][NTW];
#pragma unroll
    for (int s2 = 0; s2 < 2; ++s2) {
      size_t jcol = j0 + s2 * 32 + (size_t)(l >> 4) * 8;
#pragma unroll
      for (int nt = 0; nt < NTW; ++nt)
        bfr[s2][nt] =
            *(const short8*)&whT[(size_t)((ntb + nt) * 16 + (l & 15)) * NROW + jcol];
    }
    // prefetch next iteration's adjacency (HBM latency spans the barrier)
    AdjRaw anext = araw;
    if (it + 1 < NIT) anext = adj_load(adj, abase + (size_t)(it + 1) * 64, amode);
    int aa[8];
    adj_decode(araw, amode, aa);
    // ---- score phase: P[r, j0+sjo*8 .. +7] in bf16 into PA[cur]
    char* pab = PA[cur];
#pragma unroll
    for (int L = 0; L < NL; ++L) {
      float sv = sv_[L][sr], Mr = Ms_[L][sr];
      short8 pk;
      float ps = 0.f;
#pragma unroll
      for (int q = 0; q < 8; ++q) {
        float t = sv + ddl[cur][L][sjo * 8 + q];
        float e = fmaxf(t, 0.2f * t) - Mr;           // <= 0
        float p = aa[q] ? __expf(e) : 0.f;
        ps += p;
        pk[q] = (short)f2bf(p);
      }
      psum[L] += ps;
      *(short8*)(pab + pa_off(L, s_w, mh_w, row_w, kg_w)) = pk;
    }
    __syncthreads();                  // PA[cur] ready (ONLY barrier this iter)
    // ---- PV phase: out[r0..+32, wave n-range] += P * WhT^T  (MFMA)
    __builtin_amdgcn_s_setprio(1);
#pragma unroll
    for (int s2 = 0; s2 < 2; ++s2) {
      short8 a0 = *(const short8*)(pab + pa_off(layer, s2, 0, l & 15, l >> 4));
      short8 a1 = *(const short8*)(pab + pa_off(layer, s2, 1, l & 15, l >> 4));
#pragma unroll
      for (int nt = 0; nt < NTW; ++nt) {
        acc[0][nt] = __builtin_amdgcn_mfma_f32_16x16x32_bf16(a0, bfr[s2][nt],
                                                             acc[0][nt], 0, 0, 0);
        acc[1][nt] = __builtin_amdgcn_mfma_f32_16x16x32_bf16(a1, bfr[s2][nt],
                                                             acc[1][nt], 0, 0, 0);
      }
    }
    __builtin_amdgcn_s_setprio(0);
    // no second barrier: next score writes PA[cur^1], whose previous readers
    // (PV at it-1) completed before this iteration's barrier.
    araw = anext;
  }
  // ---- lsum: per-thread psum -> LDS (reuse PA) -> one atomic per row
  __syncthreads();                    // last PV reads of PA done
  float* red = (float*)PA;
#pragma unroll
  for (int L = 0; L < NL; ++L) red[L * 256 + sr * 8 + sjo] = psum[L];
  __syncthreads();
  if (tid < 32 * NL) {
    int L = tid >> 5, r = tid & 31;
    float t = 0.f;
#pragma unroll
    for (int q = 0; q < 8; ++q) t += red[L * 256 + r * 8 + q];
    atomicAdd(&(L ? lsb : lsa)[r0 + r], t);
  }
  // ---- accumulator flush (C/D layout: col=lane&15, row=(lane>>4)*4+reg)
  float* accp = layer ? accb : acca;
#pragma unroll
  for (int m = 0; m < 2; ++m)
#pragma unroll
    for (int nt = 0; nt < NTW; ++nt)
#pragma unroll
      for (int q = 0; q < 4; ++q)
        atomicAdd(&accp[(size_t)(r0 + m * 16 + (l >> 4) * 4 + q) * FDIM +
                        (ntb + nt) * 16 + (l & 15)],
                  acc[m][nt][q]);
}

// hbf = bf16(elu(acc/lsum)) (layer 1). n = 8192*256. fp32 h is dropped.
__global__ __launch_bounds__(256) void combine_elu(const float* __restrict__ acc_g,
    const float* __restrict__ lsum_g, u16* __restrict__ hbf) {
  int idx = blockIdx.x * 256 + threadIdx.x;
  float x = acc_g[idx] / lsum_g[idx >> 8];
  x = (x > 0.f) ? x : (__expf(x) - 1.f);
  hbf[idx] = f2bf(x);
}

// out = acc/lsum fp32, dual store (ws buffer + d_out region). n = 8192*64.
__global__ __launch_bounds__(256) void combine_div(const float* __restrict__ acc_g,
    const float* __restrict__ lsum_g, float* __restrict__ outf, float* __restrict__ outd) {
  int idx = blockIdx.x * 256 + threadIdx.x;
  float x = acc_g[idx] / lsum_g[idx >> 6];
  outf[idx] = x;
  outd[idx] = x;
}

// logits = (mu + eps*exp(0.5*logvar)) @ Wc + bc (mu/lv fp32, rest raw). fp32 out.
__global__ __launch_bounds__(256) void logits_f32(const float* __restrict__ mu,
    const float* __restrict__ lv, const void* __restrict__ eps,
    const void* __restrict__ Wc, const void* __restrict__ bcv,
    float* __restrict__ outL, const unsigned* __restrict__ modep) {
  int f32 = (int)*modep;
  __shared__ float zs[64 * 64];
  __shared__ float wcs[64 * 16];
  int tid = threadIdx.x;
  for (int i = tid; i < 1024; i += 256) wcs[i] = ldf(Wc, i, f32);
  int rl = tid >> 2, cs = (tid & 3) * 16;
  int row = blockIdx.x * 64 + rl;
  size_t rb64 = (size_t)row * 64;
  for (int c = cs; c < cs + 16; ++c)
    zs[rl * 64 + c] = mu[rb64 + c] + ldf(eps, rb64 + c, f32) * __expf(0.5f * lv[rb64 + c]);
  __syncthreads();
  for (int it = tid; it < 1024; it += 256) {
    int r = it >> 4, oc = it & 15;
    float a = ldf(bcv, oc, f32);
    for (int c = 0; c < 64; ++c) a += zs[r * 64 + c] * wcs[c * 16 + oc];
    outL[(size_t)(blockIdx.x * 64 + r) * 16 + oc] = a;
  }
}

extern "C" void kernel_launch(void* const* d_in, const int* in_sizes, int n_in,
                              void* d_out, int out_size, void* d_ws, size_t ws_size,
                              hipStream_t stream) {
  (void)out_size; (void)ws_size;
  // ---- size-based input resolution (robust to permutation; ties in dict order)
  int ix = 0, iadj = 1, ieps = 2, iW1 = 3, ia1 = 4, iWmu = 5, iamu = 6,
      iWlv = 7, ialv = 8, iWc = 9, ibc = 10;
  {
    int fmu = -1, flv = -1, fam = -1, fal = -1;
    for (int i = 0; i < n_in; ++i) {
      switch (in_sizes[i]) {
        case 67108864: iadj = i; break;
        case 4194304:  ix   = i; break;
        case 524288:   ieps = i; break;
        case 131072:   iW1  = i; break;
        case 512:      ia1  = i; break;
        case 1024:     iWc  = i; break;
        case 16:       ibc  = i; break;
        case 16384:    if (fmu < 0) fmu = i; else flv = i; break;
        case 128:      if (fam < 0) fam = i; else fal = i; break;
        default: break;
      }
    }
    if (fmu >= 0 && flv >= 0) { iWmu = fmu; iWlv = flv; }
    if (fam >= 0 && fal >= 0) { iamu = fam; ialv = fal; }
  }
  const void* adj = d_in[iadj];
  char* ws = (char*)d_ws;
  const size_t KB = 1024, MB = 1024 * 1024;
  // ---- workspace (<= 24.6 MB) ----
  float* wh1   = (float*)(ws + 0);                 // 8MB [dead after sd1/transpose1]
  float* whmu  = (float*)(ws + 0);                 // 2MB [overlay]
  float* whlv  = (float*)(ws + 2 * MB);            // 2MB [overlay]
  float* muf   = (float*)(ws + 4 * MB);            // 2MB [overlay]
  float* lvf   = (float*)(ws + 6 * MB);            // 2MB [overlay]
  u16*   xbf   = (u16*)(ws + 8 * MB);              // 8MB bf16 x [dead after gemm1]
  u16*   whT1  = (u16*)(ws + 8 * MB);              // 4MB bf16 [256][8192] [overlay]
  u16*   hbf   = (u16*)(ws + 12 * MB);             // 4MB bf16 [8192][256]
  float* hacc  = (float*)(ws + 16 * MB);           // 8MB [dead after combine1]
  float* macc  = (float*)(ws + 16 * MB);           // 2MB [overlay, memset mid-stream]
  float* lvacc = (float*)(ws + 18 * MB);           // 2MB [overlay, memset mid-stream]
  u16*   whmuT = (u16*)(ws + 20 * MB);             // 1MB bf16 [64][8192]
  u16*   whlvT = (u16*)(ws + 21 * MB);             // 1MB bf16 [64][8192]
  u16*   W1T   = (u16*)(ws + 22 * MB);             // 256KB bf16 [256][512]
  u16*   WmuT  = (u16*)(ws + 22 * MB + 256 * KB);  // 32KB bf16 [64][256]
  u16*   WlvT  = (u16*)(ws + 22 * MB + 288 * KB);  // 32KB bf16 [64][256]
  float* lsum1 = (float*)(ws + 24 * MB);           // 32KB
  float* lsmu  = (float*)(ws + 24 * MB + 32 * KB);
  float* lslv  = (float*)(ws + 24 * MB + 64 * KB);
  float* s1    = (float*)(ws + 24 * MB + 96 * KB);
  float* d1    = (float*)(ws + 24 * MB + 128 * KB);
  float* smu   = (float*)(ws + 24 * MB + 160 * KB);
  float* dmu   = (float*)(ws + 24 * MB + 192 * KB);
  float* slv   = (float*)(ws + 24 * MB + 224 * KB);
  float* dlv   = (float*)(ws + 24 * MB + 256 * KB);
  float* dmaxv = (float*)(ws + 24 * MB + 288 * KB);  // 3 cells, 64B apart
  unsigned* mode  = (unsigned*)(ws + 24 * MB + 289 * KB);
  unsigned* amode = (unsigned*)(ws + 24 * MB + 290 * KB);

  // fp32 output layout: [logits 8192*16 | mu 8192*64 | logvar 8192*64]
  float* out_logits = (float*)d_out;
  float* out_mu     = (float*)d_out + 131072;
  float* out_lv     = (float*)d_out + 655360;

  (void)hipMemsetAsync(lsum1, 0, 96 * KB, stream);        // lsum1+lsmu+lslv
  (void)hipMemsetAsync(hacc, 0, 8 * MB, stream);
  detect3<<<1, 256, 0, stream>>>((const u16*)d_in[ix], mode);
  detect_adj<<<1, 256, 0, stream>>>((const unsigned*)adj, amode);

  // layer 1: xbf/W1T bf16, Wh1 = xbf @ W1T^T (MFMA), WhT1 bf16, s/d + dmax,
  // MFMA flash (JS=8, 2048 blocks, 1 barrier/iter), combine+elu -> hbf
  convert_bf16<<<2048, 256, 0, stream>>>(d_in[ix], xbf, 524288, mode);
  transpose_any<<<dim3(16, 8), 256, 0, stream>>>(d_in[iW1], W1T, 512, 256, mode);
  gemm_mfma<<<dim3(4, 128), 256, 0, stream>>>(xbf, W1T, wh1, 512, 256);
  transpose_bf16<<<dim3(256, 8), 256, 0, stream>>>(wh1, whT1, 8192, 256);
  sd_f32<<<2048, 256, 0, stream>>>(wh1, d_in[ia1], s1, d1, 256, mode);
  dmax_reduce<<<1, 256, 0, stream>>>(d1, d1, dmaxv + 0);
  flash_mfma<1, 256, 8><<<2048, 256, 0, stream>>>(whT1, nullptr, s1, d1,
      nullptr, nullptr, dmaxv + 0, nullptr, adj, amode, hacc, lsum1, nullptr, nullptr);
  combine_elu<<<8192, 256, 0, stream>>>(hacc, lsum1, hbf);

  // zero layer-2/3 accumulators (overlaying dead hacc; stream-ordered)
  (void)hipMemsetAsync(macc, 0, 4 * MB, stream);          // macc + lvacc

  // layers 2/3: dual MFMA GEMM from hbf, dual transposes, dual s/d + dmax,
  // FUSED flash
  transpose_w2<<<dim3(8, 2, 2), 256, 0, stream>>>(d_in[iWmu], d_in[iWlv],
      WmuT, WlvT, 256, 64, mode);
  gemm2_dual<<<dim3(2, 128), 256, 0, stream>>>(hbf, WmuT, WlvT, whmu, whlv);
  transpose_pair<<<dim3(256, 2, 2), 256, 0, stream>>>(whmu, whlv, whmuT, whlvT,
      8192, 64);
  sd_dual<<<dim3(2048, 2), 256, 0, stream>>>(whmu, whlv, d_in[iamu], d_in[ialv],
      smu, slv, dmu, dlv, mode);
  dmax_reduce<<<2, 256, 0, stream>>>(dmu, dlv, dmaxv + 16);
  flash_mfma<2, 64, 8><<<2048, 256, 0, stream>>>(whmuT, whlvT, smu, dmu, slv, dlv,
      dmaxv + 16, dmaxv + 32, adj, amode, macc, lsmu, lvacc, lslv);
  combine_div<<<2048, 256, 0, stream>>>(macc, lsmu, muf, out_mu);
  combine_div<<<2048, 256, 0, stream>>>(lvacc, lslv, lvf, out_lv);

  logits_f32<<<128, 256, 0, stream>>>(muf, lvf, d_in[ieps], d_in[iWc], d_in[ibc], out_logits, mode);
}

// Round 5
// 673.874 us; speedup vs baseline: 3.0906x; 1.0241x over previous
//
#include <hip/hip_runtime.h>

typedef unsigned short u16;
typedef __attribute__((ext_vector_type(8))) short short8;
typedef __attribute__((ext_vector_type(4))) float f32x4;

#define NROW 8192

__device__ __forceinline__ float bf2f(u16 h) {
  unsigned u = ((unsigned)h) << 16;
  return __builtin_bit_cast(float, u);
}
// mode-aware load: f32 ? fp32 storage : bf16 storage (upcast)
__device__ __forceinline__ float ldf(const void* p, size_t i, int f32) {
  return f32 ? ((const float*)p)[i] : bf2f(((const u16*)p)[i]);
}
// fp32 -> bf16 round-to-nearest-even
__device__ __forceinline__ u16 f2bf(float f) {
  unsigned b = __builtin_bit_cast(unsigned, f);
  b += 0x7FFFu + ((b >> 16) & 1u);
  return (u16)(b >> 16);
}

// ---- storage-dtype detection on x (N(0,1)).
__global__ void detect3(const u16* __restrict__ xr, unsigned* __restrict__ mode) {
  __shared__ int zc, bg;
  int t = threadIdx.x;   // 256
  if (t == 0) { zc = 0; bg = 0; }
  __syncthreads();
  int zeros_even = 0; int big = 0;
  for (int i = t; i < 4096; i += 256) {
    u16 v = xr[i];
    if (!(i & 1) && v == 0) zeros_even++;
    if (fabsf(bf2f(v)) > 1e6f) big = 1;
  }
  atomicAdd(&zc, zeros_even);
  if (big) atomicOr(&bg, 1);
  __syncthreads();
  if (t == 0) *mode = (zc > 512 || bg) ? 1u : 0u;   // 1 = fp32 storage
}

// ---- adj storage detection (u32 pair pattern 0x00003F80 unique to bf16).
__global__ void detect_adj(const unsigned* __restrict__ a, unsigned* __restrict__ amode) {
  __shared__ int clo;
  int t = threadIdx.x;   // 256
  if (t == 0) clo = 0;
  __syncthreads();
  int c = 0;
  for (int i = t; i < 4096; i += 256)
    if (a[i] == 0x00003F80u) c++;
  atomicAdd(&clo, c);
  __syncthreads();
  if (t == 0) *amode = (clo > 32) ? 1u : 0u;   // 1 = bf16 storage
}

// ---- raw adjacency octet (8 elements), load/decode split for prefetching
struct AdjRaw { int4 w0, w1; };
__device__ __forceinline__ AdjRaw adj_load(const void* adj, size_t base, int amode) {
  AdjRaw r;
  if (amode == 0) {          // u32 per element: 32B
    const int4* p = (const int4*)((const int*)adj + base);
    r.w0 = p[0]; r.w1 = p[1];
  } else {                   // u16 per element: 16B
    r.w0 = *(const int4*)((const u16*)adj + base);
    r.w1 = make_int4(0, 0, 0, 0);
  }
  return r;
}
__device__ __forceinline__ void adj_decode(const AdjRaw& r, int amode, int* aa) {
  if (amode == 0) {
    aa[0] = r.w0.x != 0; aa[1] = r.w0.y != 0; aa[2] = r.w0.z != 0; aa[3] = r.w0.w != 0;
    aa[4] = r.w1.x != 0; aa[5] = r.w1.y != 0; aa[6] = r.w1.z != 0; aa[7] = r.w1.w != 0;
  } else {
    aa[0] = (r.w0.x & 0xFFFF) != 0; aa[1] = ((unsigned)r.w0.x >> 16) != 0;
    aa[2] = (r.w0.y & 0xFFFF) != 0; aa[3] = ((unsigned)r.w0.y >> 16) != 0;
    aa[4] = (r.w0.z & 0xFFFF) != 0; aa[5] = ((unsigned)r.w0.z >> 16) != 0;
    aa[6] = (r.w0.w & 0xFFFF) != 0; aa[7] = ((unsigned)r.w0.w >> 16) != 0;
  }
}

// C[M x N] fp32 = Abf[M x K] @ BT[N x K]^T, all bf16 operands, MFMA, no LDS.
// grid (N/64, M/64), 256 threads; wave w owns rows w*16..+15, 4 n-tiles.
__global__ __launch_bounds__(256) void gemm_mfma(const u16* __restrict__ Abf,
    const u16* __restrict__ BT, float* __restrict__ C, int K, int N) {
  int tid = threadIdx.x;
  int l = tid & 63, w = tid >> 6;
  int m0 = blockIdx.y * 64, n0 = blockIdx.x * 64;
  const u16* arow = Abf + (size_t)(m0 + w * 16 + (l & 15)) * K + (l >> 4) * 8;
  const u16* brow = BT + (size_t)(n0 + (l & 15)) * K + (l >> 4) * 8;
  f32x4 acc[4];
#pragma unroll
  for (int nt = 0; nt < 4; ++nt) acc[nt] = (f32x4){0.f, 0.f, 0.f, 0.f};
  for (int k0 = 0; k0 < K; k0 += 32) {
    short8 a = *(const short8*)(arow + k0);
#pragma unroll
    for (int nt = 0; nt < 4; ++nt) {
      short8 b = *(const short8*)(brow + (size_t)nt * 16 * K + k0);
      acc[nt] = __builtin_amdgcn_mfma_f32_16x16x32_bf16(a, b, acc[nt], 0, 0, 0);
    }
  }
  // C/D layout: col = lane&15, row = (lane>>4)*4 + q
#pragma unroll
  for (int nt = 0; nt < 4; ++nt)
#pragma unroll
    for (int q = 0; q < 4; ++q)
      C[(size_t)(m0 + w * 16 + (l >> 4) * 4 + q) * N + n0 + nt * 16 + (l & 15)] =
          acc[nt][q];
}

// Layer-2/3 dual GEMM: C{0,1}[8192 x 64] fp32 = hbf[8192 x 256] @ BT{0,1}[64 x 256]^T.
// grid (2, 128): blockIdx.x selects matrix; 256 blocks fill the GPU.
__global__ __launch_bounds__(256) void gemm2_dual(const u16* __restrict__ Abf,
    const u16* __restrict__ BT0, const u16* __restrict__ BT1,
    float* __restrict__ C0, float* __restrict__ C1) {
  const int K = 256, N = 64;
  const u16* BT = blockIdx.x ? BT1 : BT0;
  float* C = blockIdx.x ? C1 : C0;
  int tid = threadIdx.x, l = tid & 63, w = tid >> 6;
  int m0 = blockIdx.y * 64;
  const u16* arow = Abf + (size_t)(m0 + w * 16 + (l & 15)) * K + (l >> 4) * 8;
  const u16* brow = BT + (size_t)(l & 15) * K + (l >> 4) * 8;
  f32x4 acc[4];
#pragma unroll
  for (int nt = 0; nt < 4; ++nt) acc[nt] = (f32x4){0.f, 0.f, 0.f, 0.f};
  for (int k0 = 0; k0 < K; k0 += 32) {
    short8 a = *(const short8*)(arow + k0);
#pragma unroll
    for (int nt = 0; nt < 4; ++nt) {
      short8 b = *(const short8*)(brow + (size_t)nt * 16 * K + k0);
      acc[nt] = __builtin_amdgcn_mfma_f32_16x16x32_bf16(a, b, acc[nt], 0, 0, 0);
    }
  }
#pragma unroll
  for (int nt = 0; nt < 4; ++nt)
#pragma unroll
    for (int q = 0; q < 4; ++q)
      C[(size_t)(m0 + w * 16 + (l >> 4) * 4 + q) * N + nt * 16 + (l & 15)] = acc[nt][q];
}

// bf16 copy of a mode-aware buffer (8 elems/thread). n8 = elems/8.
__global__ __launch_bounds__(256) void convert_bf16(const void* __restrict__ in,
    u16* __restrict__ out, int n8, const unsigned* __restrict__ modep) {
  int f32 = (int)*modep;
  int i = blockIdx.x * 256 + threadIdx.x;
  if (i >= n8) return;
  if (f32) {
    float4 v0 = ((const float4*)in)[(size_t)i * 2];
    float4 v1 = ((const float4*)in)[(size_t)i * 2 + 1];
    ushort4 o0 = {f2bf(v0.x), f2bf(v0.y), f2bf(v0.z), f2bf(v0.w)};
    ushort4 o1 = {f2bf(v1.x), f2bf(v1.y), f2bf(v1.z), f2bf(v1.w)};
    ((ushort4*)out)[(size_t)i * 2] = o0;
    ((ushort4*)out)[(size_t)i * 2 + 1] = o1;
  } else {
    ((int4*)out)[i] = ((const int4*)in)[i];   // already bf16: raw copy
  }
}

// transpose + bf16 convert: in fp32 [M][F] -> out bf16 [F][M]. grid (M/32, F/32).
__global__ __launch_bounds__(256) void transpose_bf16(const float* __restrict__ in,
    u16* __restrict__ out, int M, int F) {
  __shared__ float t[32][33];
  int m0 = blockIdx.x * 32, f0 = blockIdx.y * 32;
  int c = threadIdx.x & 31, r = threadIdx.x >> 5;   // r = 0..7
  for (int rr = r; rr < 32; rr += 8)
    t[rr][c] = in[(size_t)(m0 + rr) * F + f0 + c];
  __syncthreads();
  for (int rr = r; rr < 32; rr += 8)
    out[(size_t)(f0 + rr) * M + m0 + c] = f2bf(t[c][rr]);
}

// dual fp32->bf16 transpose (whmu/whlv -> whmuT/whlvT). grid (M/32, F/32, 2).
__global__ __launch_bounds__(256) void transpose_pair(const float* __restrict__ in0,
    const float* __restrict__ in1, u16* __restrict__ out0, u16* __restrict__ out1,
    int M, int F) {
  const float* in = blockIdx.z ? in1 : in0;
  u16* out = blockIdx.z ? out1 : out0;
  __shared__ float t[32][33];
  int m0 = blockIdx.x * 32, f0 = blockIdx.y * 32;
  int c = threadIdx.x & 31, r = threadIdx.x >> 5;
  for (int rr = r; rr < 32; rr += 8)
    t[rr][c] = in[(size_t)(m0 + rr) * F + f0 + c];
  __syncthreads();
  for (int rr = r; rr < 32; rr += 8)
    out[(size_t)(f0 + rr) * M + m0 + c] = f2bf(t[c][rr]);
}

// transpose + bf16 convert from a RAW (mode-aware) buffer. grid (M/32, F/32).
__global__ __launch_bounds__(256) void transpose_any(const void* __restrict__ in,
    u16* __restrict__ out, int M, int F, const unsigned* __restrict__ modep) {
  int f32 = (int)*modep;
  __shared__ u16 t[32][33];
  int m0 = blockIdx.x * 32, f0 = blockIdx.y * 32;
  int c = threadIdx.x & 31, r = threadIdx.x >> 5;
  for (int rr = r; rr < 32; rr += 8)
    t[rr][c] = f2bf(ldf(in, (size_t)(m0 + rr) * F + f0 + c, f32));
  __syncthreads();
  for (int rr = r; rr < 32; rr += 8)
    out[(size_t)(f0 + rr) * M + m0 + c] = t[c][rr];
}

// dual raw transpose (Wmu/Wlv -> WmuT/WlvT). grid (M/32, F/32, 2).
__global__ __launch_bounds__(256) void transpose_w2(const void* __restrict__ in0,
    const void* __restrict__ in1, u16* __restrict__ out0, u16* __restrict__ out1,
    int M, int F, const unsigned* __restrict__ modep) {
  int f32 = (int)*modep;
  const void* in = blockIdx.z ? in1 : in0;
  u16* out = blockIdx.z ? out1 : out0;
  __shared__ u16 t[32][33];
  int m0 = blockIdx.x * 32, f0 = blockIdx.y * 32;
  int c = threadIdx.x & 31, r = threadIdx.x >> 5;
  for (int rr = r; rr < 32; rr += 8)
    t[rr][c] = f2bf(ldf(in, (size_t)(m0 + rr) * F + f0 + c, f32));
  __syncthreads();
  for (int rr = r; rr < 32; rr += 8)
    out[(size_t)(f0 + rr) * M + m0 + c] = t[c][rr];
}

// s_i = Wh_i . a[:F], d_i = Wh_i . a[F:] (Wh fp32, a raw). NO atomics.
__global__ __launch_bounds__(256) void sd_f32(const float* __restrict__ Wh,
    const void* __restrict__ a2, float* __restrict__ s, float* __restrict__ d,
    int F, const unsigned* __restrict__ modep) {
  int f32 = (int)*modep;
  int row = blockIdx.x * 4 + (threadIdx.x >> 6);
  int l = threadIdx.x & 63;
  float ss = 0.f, dd = 0.f;
  for (int k = l; k < F; k += 64) {
    float wv = Wh[(size_t)row * F + k];
    ss += wv * ldf(a2, k, f32);
    dd += wv * ldf(a2, F + k, f32);
  }
#pragma unroll
  for (int off = 32; off > 0; off >>= 1) {
    ss += __shfl_down(ss, off, 64);
    dd += __shfl_down(dd, off, 64);
  }
  if (l == 0) { s[row] = ss; d[row] = dd; }
}

// dual s/d for layers 2/3 (F = 64). grid (2048, 2). NO atomics.
__global__ __launch_bounds__(256) void sd_dual(const float* __restrict__ Wh0,
    const float* __restrict__ Wh1, const void* __restrict__ a0,
    const void* __restrict__ a1, float* __restrict__ s0, float* __restrict__ s1,
    float* __restrict__ d0, float* __restrict__ d1,
    const unsigned* __restrict__ modep) {
  int f32 = (int)*modep;
  int L = blockIdx.y;
  const float* Wh = L ? Wh1 : Wh0;
  const void* a2 = L ? a1 : a0;
  int row = blockIdx.x * 4 + (threadIdx.x >> 6);
  int l = threadIdx.x & 63;
  float wv = Wh[(size_t)row * 64 + l];
  float ss = wv * ldf(a2, l, f32);
  float dd = wv * ldf(a2, 64 + l, f32);
#pragma unroll
  for (int off = 32; off > 0; off >>= 1) {
    ss += __shfl_down(ss, off, 64);
    dd += __shfl_down(dd, off, 64);
  }
  if (l == 0) { (L ? s1 : s0)[row] = ss; (L ? d1 : d0)[row] = dd; }
}

// Dmax: single block per array, LDS tree, plain store (no atomics, no
// contention). grid = #arrays; writes cells[blockIdx.x * 16] (64B apart).
__global__ __launch_bounds__(256) void dmax_reduce(const float* __restrict__ da,
    const float* __restrict__ db, float* __restrict__ cells) {
  const float* d = blockIdx.x ? db : da;
  __shared__ float red[256];
  float m = -3.4e38f;
  for (int i = threadIdx.x; i < NROW; i += 256) m = fmaxf(m, d[i]);
  red[threadIdx.x] = m;
  __syncthreads();
#pragma unroll
  for (int sft = 128; sft > 0; sft >>= 1) {
    if (threadIdx.x < sft) red[threadIdx.x] = fmaxf(red[threadIdx.x], red[threadIdx.x + sft]);
    __syncthreads();
  }
  if (threadIdx.x == 0) cells[blockIdx.x * 16] = red[0];
}

// swizzled P-fragment LDS byte offset: [L][s][mh][row 0..15][kg 0..3] x 8 bf16
__device__ __forceinline__ int pa_off(int L, int s, int mh, int row, int kg) {
  return ((L * 4 + s * 2 + mh) << 10) + (row << 6) + ((kg ^ ((row >> 1) & 3)) << 4);
}

// Flash GAT layer(s) on MFMA. R=32 rows/block, 64-j tile per iteration.
// Pipelined K-loop, NO vmcnt drain at the barrier:
//   - raw s_barrier + manual lgkmcnt(0) (LDS visibility only) so adjacency
//     and B-fragment global loads stay in flight across iterations (T3/T4).
//   - adjacency register-prefetched DEPTH 2 (static rotation).
//   - d_j slice staged ONCE into LDS in the prologue (no per-iter staging).
// PA double-buffered; score(t+1) overlaps MFMA of PV(t). setprio on MFMA.
template <int NL, int FDIM, int JS>
__global__ __launch_bounds__(256) void flash_mfma(
    const u16* __restrict__ whTa, const u16* __restrict__ whTb,   // bf16 [FDIM][NROW]
    const float* __restrict__ sa, const float* __restrict__ da,
    const float* __restrict__ sb, const float* __restrict__ db,
    const float* __restrict__ cella, const float* __restrict__ cellb,
    const void* __restrict__ adj, const unsigned* __restrict__ amodep,
    float* __restrict__ acca, float* __restrict__ lsa,
    float* __restrict__ accb, float* __restrict__ lsb) {
  constexpr int JLEN = NROW / JS;
  constexpr int NIT = JLEN / 64;
  constexpr int NTW = (NL == 1) ? 4 : 2;     // n-tiles per wave
  constexpr int NRBLK = NROW / 32;
  __shared__ __align__(16) char PA[2][NL * 4096];   // double-buffered P frags
  __shared__ __align__(16) float dd_[NL][JLEN];     // whole d_j slice (prologue)
  __shared__ float sv_[NL][32], Ms_[NL][32];
  int tid = threadIdx.x;
  int amode = (int)*amodep;
  int rblk = blockIdx.x % NRBLK, js = blockIdx.x / NRBLK;
  int r0 = rblk * 32;
  size_t jbase = (size_t)js * JLEN;
  if (tid < 32 * NL) {
    int L = tid >> 5, i = tid & 31;
    float Dm = L ? *cellb : *cella;
    float t0 = (L ? sb : sa)[r0 + i];
    sv_[L][i] = t0;
    float m = t0 + Dm;
    Ms_[L][i] = fmaxf(m, 0.2f * m);   // lrelu(s_i + Dmax) >= all e[i,:]
  }
  // stage the full d_j slice for this block's j-range (float4 coalesced)
  for (int u = tid; u < (NL * JLEN) / 4; u += 256) {
    int L = u / (JLEN / 4), uu = u - L * (JLEN / 4);
    ((float4*)dd_[L])[uu] = ((const float4*)((L ? db : da) + jbase))[uu];
  }
  __syncthreads();
  // score-phase mapping: 32 rows x 8 j-octets
  int sr = tid >> 3, sjo = tid & 7;
  int s_w = sjo >> 2, kg_w = sjo & 3, mh_w = sr >> 4, row_w = sr & 15;
  // PV-phase mapping
  int l = tid & 63, w = tid >> 6;
  int layer = (NL == 1) ? 0 : (w >> 1);
  int ntb = (NL == 1) ? (w * 4) : ((w & 1) * 2);
  const u16* whT = layer ? whTb : whTa;
  f32x4 acc[2][NTW];
#pragma unroll
  for (int m = 0; m < 2; ++m)
#pragma unroll
    for (int n = 0; n < NTW; ++n) acc[m][n] = (f32x4){0.f, 0.f, 0.f, 0.f};
  float psum[NL];
#pragma unroll
  for (int L = 0; L < NL; ++L) psum[L] = 0.f;
  size_t abase = (size_t)(r0 + sr) * NROW + jbase + sjo * 8;

  // adjacency prefetch: depth 2 (static rotation adjA <- adjB <- adjN)
  AdjRaw adjA = adj_load(adj, abase, amode);
  AdjRaw adjB = (NIT > 1) ? adj_load(adj, abase + 64, amode) : adjA;
  for (int it = 0; it < NIT; ++it) {
    size_t j0 = jbase + (size_t)it * 64;
    int cur = it & 1;
    // B fragments for this tile (issued first so the PV-time wait for them
    // leaves the later-issued adj prefetch in flight; L2-latency hidden
    // under the score phase)
    short8 bfr[2][NTW];
#pragma unroll
    for (int s2 = 0; s2 < 2; ++s2) {
      size_t jcol = j0 + s2 * 32 + (size_t)(l >> 4) * 8;
#pragma unroll
      for (int nt = 0; nt < NTW; ++nt)
        bfr[s2][nt] =
            *(const short8*)&whT[(size_t)((ntb + nt) * 16 + (l & 15)) * NROW + jcol];
    }
    // prefetch adjacency two iterations ahead
    AdjRaw adjN = adjB;
    if (it + 2 < NIT) adjN = adj_load(adj, abase + (size_t)(it + 2) * 64, amode);
    int aa[8];
    adj_decode(adjA, amode, aa);            // data already drained (age 2 iters)
    // ---- score phase: P[r, j0+sjo*8 .. +7] in bf16 into PA[cur]
    char* pab = PA[cur];
#pragma unroll
    for (int L = 0; L < NL; ++L) {
      float sv = sv_[L][sr], Mr = Ms_[L][sr];
      float4 dv0 = *(const float4*)&dd_[L][it * 64 + sjo * 8];
      float4 dv1 = *(const float4*)&dd_[L][it * 64 + sjo * 8 + 4];
      float dvv[8] = {dv0.x, dv0.y, dv0.z, dv0.w, dv1.x, dv1.y, dv1.z, dv1.w};
      short8 pk;
      float ps = 0.f;
#pragma unroll
      for (int q = 0; q < 8; ++q) {
        float t = sv + dvv[q];
        float e = fmaxf(t, 0.2f * t) - Mr;           // <= 0
        float p = aa[q] ? __expf(e) : 0.f;
        ps += p;
        pk[q] = (short)f2bf(p);
      }
      psum[L] += ps;
      *(short8*)(pab + pa_off(L, s_w, mh_w, row_w, kg_w)) = pk;
    }
    // LDS-only fence + RAW barrier: PA writes visible, global loads (adj,
    // bfr of future iterations) remain outstanding across the barrier.
    asm volatile("s_waitcnt lgkmcnt(0)" ::: "memory");
    __builtin_amdgcn_s_barrier();
    __builtin_amdgcn_sched_barrier(0);
    // ---- PV phase: out[r0..+32, wave n-range] += P * WhT^T  (MFMA)
    __builtin_amdgcn_s_setprio(1);
#pragma unroll
    for (int s2 = 0; s2 < 2; ++s2) {
      short8 a0 = *(const short8*)(pab + pa_off(layer, s2, 0, l & 15, l >> 4));
      short8 a1 = *(const short8*)(pab + pa_off(layer, s2, 1, l & 15, l >> 4));
#pragma unroll
      for (int nt = 0; nt < NTW; ++nt) {
        acc[0][nt] = __builtin_amdgcn_mfma_f32_16x16x32_bf16(a0, bfr[s2][nt],
                                                             acc[0][nt], 0, 0, 0);
        acc[1][nt] = __builtin_amdgcn_mfma_f32_16x16x32_bf16(a1, bfr[s2][nt],
                                                             acc[1][nt], 0, 0, 0);
      }
    }
    __builtin_amdgcn_s_setprio(0);
    // no second barrier: next score writes PA[cur^1], whose previous readers
    // (PV at it-1) completed before this iteration's barrier.
    adjA = adjB; adjB = adjN;
  }
  // ---- lsum: per-thread psum -> LDS (reuse PA) -> one atomic per row
  __syncthreads();                    // full drain OK (once per block)
  float* red = (float*)PA;
#pragma unroll
  for (int L = 0; L < NL; ++L) red[L * 256 + sr * 8 + sjo] = psum[L];
  __syncthreads();
  if (tid < 32 * NL) {
    int L = tid >> 5, r = tid & 31;
    float t = 0.f;
#pragma unroll
    for (int q = 0; q < 8; ++q) t += red[L * 256 + r * 8 + q];
    atomicAdd(&(L ? lsb : lsa)[r0 + r], t);
  }
  // ---- accumulator flush (C/D layout: col=lane&15, row=(lane>>4)*4+reg)
  float* accp = layer ? accb : acca;
#pragma unroll
  for (int m = 0; m < 2; ++m)
#pragma unroll
    for (int nt = 0; nt < NTW; ++nt)
#pragma unroll
      for (int q = 0; q < 4; ++q)
        atomicAdd(&accp[(size_t)(r0 + m * 16 + (l >> 4) * 4 + q) * FDIM +
                        (ntb + nt) * 16 + (l & 15)],
                  acc[m][nt][q]);
}

// hbf = bf16(elu(acc/lsum)) (layer 1). n = 8192*256. fp32 h is dropped.
__global__ __launch_bounds__(256) void combine_elu(const float* __restrict__ acc_g,
    const float* __restrict__ lsum_g, u16* __restrict__ hbf) {
  int idx = blockIdx.x * 256 + threadIdx.x;
  float x = acc_g[idx] / lsum_g[idx >> 8];
  x = (x > 0.f) ? x : (__expf(x) - 1.f);
  hbf[idx] = f2bf(x);
}

// out = acc/lsum fp32, dual store (ws buffer + d_out region). n = 8192*64.
__global__ __launch_bounds__(256) void combine_div(const float* __restrict__ acc_g,
    const float* __restrict__ lsum_g, float* __restrict__ outf, float* __restrict__ outd) {
  int idx = blockIdx.x * 256 + threadIdx.x;
  float x = acc_g[idx] / lsum_g[idx >> 6];
  outf[idx] = x;
  outd[idx] = x;
}

// logits = (mu + eps*exp(0.5*logvar)) @ Wc + bc (mu/lv fp32, rest raw). fp32 out.
__global__ __launch_bounds__(256) void logits_f32(const float* __restrict__ mu,
    const float* __restrict__ lv, const void* __restrict__ eps,
    const void* __restrict__ Wc, const void* __restrict__ bcv,
    float* __restrict__ outL, const unsigned* __restrict__ modep) {
  int f32 = (int)*modep;
  __shared__ float zs[64 * 64];
  __shared__ float wcs[64 * 16];
  int tid = threadIdx.x;
  for (int i = tid; i < 1024; i += 256) wcs[i] = ldf(Wc, i, f32);
  int rl = tid >> 2, cs = (tid & 3) * 16;
  int row = blockIdx.x * 64 + rl;
  size_t rb64 = (size_t)row * 64;
  for (int c = cs; c < cs + 16; ++c)
    zs[rl * 64 + c] = mu[rb64 + c] + ldf(eps, rb64 + c, f32) * __expf(0.5f * lv[rb64 + c]);
  __syncthreads();
  for (int it = tid; it < 1024; it += 256) {
    int r = it >> 4, oc = it & 15;
    float a = ldf(bcv, oc, f32);
    for (int c = 0; c < 64; ++c) a += zs[r * 64 + c] * wcs[c * 16 + oc];
    outL[(size_t)(blockIdx.x * 64 + r) * 16 + oc] = a;
  }
}

extern "C" void kernel_launch(void* const* d_in, const int* in_sizes, int n_in,
                              void* d_out, int out_size, void* d_ws, size_t ws_size,
                              hipStream_t stream) {
  (void)out_size; (void)ws_size;
  // ---- size-based input resolution (robust to permutation; ties in dict order)
  int ix = 0, iadj = 1, ieps = 2, iW1 = 3, ia1 = 4, iWmu = 5, iamu = 6,
      iWlv = 7, ialv = 8, iWc = 9, ibc = 10;
  {
    int fmu = -1, flv = -1, fam = -1, fal = -1;
    for (int i = 0; i < n_in; ++i) {
      switch (in_sizes[i]) {
        case 67108864: iadj = i; break;
        case 4194304:  ix   = i; break;
        case 524288:   ieps = i; break;
        case 131072:   iW1  = i; break;
        case 512:      ia1  = i; break;
        case 1024:     iWc  = i; break;
        case 16:       ibc  = i; break;
        case 16384:    if (fmu < 0) fmu = i; else flv = i; break;
        case 128:      if (fam < 0) fam = i; else fal = i; break;
        default: break;
      }
    }
    if (fmu >= 0 && flv >= 0) { iWmu = fmu; iWlv = flv; }
    if (fam >= 0 && fal >= 0) { iamu = fam; ialv = fal; }
  }
  const void* adj = d_in[iadj];
  char* ws = (char*)d_ws;
  const size_t KB = 1024, MB = 1024 * 1024;
  // ---- workspace (<= 24.6 MB) ----
  float* wh1   = (float*)(ws + 0);                 // 8MB [dead after sd1/transpose1]
  float* whmu  = (float*)(ws + 0);                 // 2MB [overlay]
  float* whlv  = (float*)(ws + 2 * MB);            // 2MB [overlay]
  float* muf   = (float*)(ws + 4 * MB);            // 2MB [overlay]
  float* lvf   = (float*)(ws + 6 * MB);            // 2MB [overlay]
  u16*   xbf   = (u16*)(ws + 8 * MB);              // 8MB bf16 x [dead after gemm1]
  u16*   whT1  = (u16*)(ws + 8 * MB);              // 4MB bf16 [256][8192] [overlay]
  u16*   hbf   = (u16*)(ws + 12 * MB);             // 4MB bf16 [8192][256]
  float* hacc  = (float*)(ws + 16 * MB);           // 8MB [dead after combine1]
  float* macc  = (float*)(ws + 16 * MB);           // 2MB [overlay, memset mid-stream]
  float* lvacc = (float*)(ws + 18 * MB);           // 2MB [overlay, memset mid-stream]
  u16*   whmuT = (u16*)(ws + 20 * MB);             // 1MB bf16 [64][8192]
  u16*   whlvT = (u16*)(ws + 21 * MB);             // 1MB bf16 [64][8192]
  u16*   W1T   = (u16*)(ws + 22 * MB);             // 256KB bf16 [256][512]
  u16*   WmuT  = (u16*)(ws + 22 * MB + 256 * KB);  // 32KB bf16 [64][256]
  u16*   WlvT  = (u16*)(ws + 22 * MB + 288 * KB);  // 32KB bf16 [64][256]
  float* lsum1 = (float*)(ws + 24 * MB);           // 32KB
  float* lsmu  = (float*)(ws + 24 * MB + 32 * KB);
  float* lslv  = (float*)(ws + 24 * MB + 64 * KB);
  float* s1    = (float*)(ws + 24 * MB + 96 * KB);
  float* d1    = (float*)(ws + 24 * MB + 128 * KB);
  float* smu   = (float*)(ws + 24 * MB + 160 * KB);
  float* dmu   = (float*)(ws + 24 * MB + 192 * KB);
  float* slv   = (float*)(ws + 24 * MB + 224 * KB);
  float* dlv   = (float*)(ws + 24 * MB + 256 * KB);
  float* dmaxv = (float*)(ws + 24 * MB + 288 * KB);  // 3 cells, 64B apart
  unsigned* mode  = (unsigned*)(ws + 24 * MB + 289 * KB);
  unsigned* amode = (unsigned*)(ws + 24 * MB + 290 * KB);

  // fp32 output layout: [logits 8192*16 | mu 8192*64 | logvar 8192*64]
  float* out_logits = (float*)d_out;
  float* out_mu     = (float*)d_out + 131072;
  float* out_lv     = (float*)d_out + 655360;

  (void)hipMemsetAsync(lsum1, 0, 96 * KB, stream);        // lsum1+lsmu+lslv
  (void)hipMemsetAsync(hacc, 0, 8 * MB, stream);
  detect3<<<1, 256, 0, stream>>>((const u16*)d_in[ix], mode);
  detect_adj<<<1, 256, 0, stream>>>((const unsigned*)adj, amode);

  // layer 1: xbf/W1T bf16, Wh1 = xbf @ W1T^T (MFMA), WhT1 bf16, s/d + dmax,
  // MFMA flash (JS=8, 2048 blocks, raw-barrier pipeline), combine+elu -> hbf
  convert_bf16<<<2048, 256, 0, stream>>>(d_in[ix], xbf, 524288, mode);
  transpose_any<<<dim3(16, 8), 256, 0, stream>>>(d_in[iW1], W1T, 512, 256, mode);
  gemm_mfma<<<dim3(4, 128), 256, 0, stream>>>(xbf, W1T, wh1, 512, 256);
  transpose_bf16<<<dim3(256, 8), 256, 0, stream>>>(wh1, whT1, 8192, 256);
  sd_f32<<<2048, 256, 0, stream>>>(wh1, d_in[ia1], s1, d1, 256, mode);
  dmax_reduce<<<1, 256, 0, stream>>>(d1, d1, dmaxv + 0);
  flash_mfma<1, 256, 8><<<2048, 256, 0, stream>>>(whT1, nullptr, s1, d1,
      nullptr, nullptr, dmaxv + 0, nullptr, adj, amode, hacc, lsum1, nullptr, nullptr);
  combine_elu<<<8192, 256, 0, stream>>>(hacc, lsum1, hbf);

  // zero layer-2/3 accumulators (overlaying dead hacc; stream-ordered)
  (void)hipMemsetAsync(macc, 0, 4 * MB, stream);          // macc + lvacc

  // layers 2/3: dual MFMA GEMM from hbf, dual transposes, dual s/d + dmax,
  // FUSED flash
  transpose_w2<<<dim3(8, 2, 2), 256, 0, stream>>>(d_in[iWmu], d_in[iWlv],
      WmuT, WlvT, 256, 64, mode);
  gemm2_dual<<<dim3(2, 128), 256, 0, stream>>>(hbf, WmuT, WlvT, whmu, whlv);
  transpose_pair<<<dim3(256, 2, 2), 256, 0, stream>>>(whmu, whlv, whmuT, whlvT,
      8192, 64);
  sd_dual<<<dim3(2048, 2), 256, 0, stream>>>(whmu, whlv, d_in[iamu], d_in[ialv],
      smu, slv, dmu, dlv, mode);
  dmax_reduce<<<2, 256, 0, stream>>>(dmu, dlv, dmaxv + 16);
  flash_mfma<2, 64, 8><<<2048, 256, 0, stream>>>(whmuT, whlvT, smu, dmu, slv, dlv,
      dmaxv + 16, dmaxv + 32, adj, amode, macc, lsmu, lvacc, lslv);
  combine_div<<<2048, 256, 0, stream>>>(macc, lsmu, muf, out_mu);
  combine_div<<<2048, 256, 0, stream>>>(lvacc, lslv, lvf, out_lv);

  logits_f32<<<128, 256, 0, stream>>>(muf, lvf, d_in[ieps], d_in[iWc], d_in[ibc], out_logits, mode);
}

// Round 6
// 616.834 us; speedup vs baseline: 3.3764x; 1.0925x over previous
//
#include <hip/hip_runtime.h>

typedef unsigned short u16;
typedef __attribute__((ext_vector_type(8))) short short8;
typedef __attribute__((ext_vector_type(4))) float f32x4;

#define NROW 8192

__device__ __forceinline__ float bf2f(u16 h) {
  unsigned u = ((unsigned)h) << 16;
  return __builtin_bit_cast(float, u);
}
// mode-aware load: f32 ? fp32 storage : bf16 storage (upcast)
__device__ __forceinline__ float ldf(const void* p, size_t i, int f32) {
  return f32 ? ((const float*)p)[i] : bf2f(((const u16*)p)[i]);
}
// fp32 -> bf16 round-to-nearest-even
__device__ __forceinline__ u16 f2bf(float f) {
  unsigned b = __builtin_bit_cast(unsigned, f);
  b += 0x7FFFu + ((b >> 16) & 1u);
  return (u16)(b >> 16);
}

// ---- storage-dtype detection on x (N(0,1)).
__global__ void detect3(const u16* __restrict__ xr, unsigned* __restrict__ mode) {
  __shared__ int zc, bg;
  int t = threadIdx.x;   // 256
  if (t == 0) { zc = 0; bg = 0; }
  __syncthreads();
  int zeros_even = 0; int big = 0;
  for (int i = t; i < 4096; i += 256) {
    u16 v = xr[i];
    if (!(i & 1) && v == 0) zeros_even++;
    if (fabsf(bf2f(v)) > 1e6f) big = 1;
  }
  atomicAdd(&zc, zeros_even);
  if (big) atomicOr(&bg, 1);
  __syncthreads();
  if (t == 0) *mode = (zc > 512 || bg) ? 1u : 0u;   // 1 = fp32 storage
}

// ---- adj storage detection (u32 pair pattern 0x00003F80 unique to bf16).
__global__ void detect_adj(const unsigned* __restrict__ a, unsigned* __restrict__ amode) {
  __shared__ int clo;
  int t = threadIdx.x;   // 256
  if (t == 0) clo = 0;
  __syncthreads();
  int c = 0;
  for (int i = t; i < 4096; i += 256)
    if (a[i] == 0x00003F80u) c++;
  atomicAdd(&clo, c);
  __syncthreads();
  if (t == 0) *amode = (clo > 32) ? 1u : 0u;   // 1 = bf16 storage
}

// ---- raw adjacency octet (8 elements), load/decode split for prefetching
struct AdjRaw { int4 w0, w1; };
__device__ __forceinline__ AdjRaw adj_load(const void* adj, size_t base, int amode) {
  AdjRaw r;
  if (amode == 0) {          // u32 per element: 32B
    const int4* p = (const int4*)((const int*)adj + base);
    r.w0 = p[0]; r.w1 = p[1];
  } else {                   // u16 per element: 16B
    r.w0 = *(const int4*)((const u16*)adj + base);
    r.w1 = make_int4(0, 0, 0, 0);
  }
  return r;
}
__device__ __forceinline__ void adj_decode(const AdjRaw& r, int amode, int* aa) {
  if (amode == 0) {
    aa[0] = r.w0.x != 0; aa[1] = r.w0.y != 0; aa[2] = r.w0.z != 0; aa[3] = r.w0.w != 0;
    aa[4] = r.w1.x != 0; aa[5] = r.w1.y != 0; aa[6] = r.w1.z != 0; aa[7] = r.w1.w != 0;
  } else {
    aa[0] = (r.w0.x & 0xFFFF) != 0; aa[1] = ((unsigned)r.w0.x >> 16) != 0;
    aa[2] = (r.w0.y & 0xFFFF) != 0; aa[3] = ((unsigned)r.w0.y >> 16) != 0;
    aa[4] = (r.w0.z & 0xFFFF) != 0; aa[5] = ((unsigned)r.w0.z >> 16) != 0;
    aa[6] = (r.w0.w & 0xFFFF) != 0; aa[7] = ((unsigned)r.w0.w >> 16) != 0;
  }
}

// C[M x N] fp32 = Abf[M x K] @ BT[N x K]^T, all bf16 operands, MFMA, no LDS.
// grid (N/64, M/64), 256 threads; wave w owns rows w*16..+15, 4 n-tiles.
__global__ __launch_bounds__(256) void gemm_mfma(const u16* __restrict__ Abf,
    const u16* __restrict__ BT, float* __restrict__ C, int K, int N) {
  int tid = threadIdx.x;
  int l = tid & 63, w = tid >> 6;
  int m0 = blockIdx.y * 64, n0 = blockIdx.x * 64;
  const u16* arow = Abf + (size_t)(m0 + w * 16 + (l & 15)) * K + (l >> 4) * 8;
  const u16* brow = BT + (size_t)(n0 + (l & 15)) * K + (l >> 4) * 8;
  f32x4 acc[4];
#pragma unroll
  for (int nt = 0; nt < 4; ++nt) acc[nt] = (f32x4){0.f, 0.f, 0.f, 0.f};
  for (int k0 = 0; k0 < K; k0 += 32) {
    short8 a = *(const short8*)(arow + k0);
#pragma unroll
    for (int nt = 0; nt < 4; ++nt) {
      short8 b = *(const short8*)(brow + (size_t)nt * 16 * K + k0);
      acc[nt] = __builtin_amdgcn_mfma_f32_16x16x32_bf16(a, b, acc[nt], 0, 0, 0);
    }
  }
  // C/D layout: col = lane&15, row = (lane>>4)*4 + q
#pragma unroll
  for (int nt = 0; nt < 4; ++nt)
#pragma unroll
    for (int q = 0; q < 4; ++q)
      C[(size_t)(m0 + w * 16 + (l >> 4) * 4 + q) * N + n0 + nt * 16 + (l & 15)] =
          acc[nt][q];
}

// Layer-2/3 dual GEMM: C{0,1}[8192 x 64] fp32 = hbf[8192 x 256] @ BT{0,1}[64 x 256]^T.
// grid (2, 128): blockIdx.x selects matrix; 256 blocks fill the GPU.
__global__ __launch_bounds__(256) void gemm2_dual(const u16* __restrict__ Abf,
    const u16* __restrict__ BT0, const u16* __restrict__ BT1,
    float* __restrict__ C0, float* __restrict__ C1) {
  const int K = 256, N = 64;
  const u16* BT = blockIdx.x ? BT1 : BT0;
  float* C = blockIdx.x ? C1 : C0;
  int tid = threadIdx.x, l = tid & 63, w = tid >> 6;
  int m0 = blockIdx.y * 64;
  const u16* arow = Abf + (size_t)(m0 + w * 16 + (l & 15)) * K + (l >> 4) * 8;
  const u16* brow = BT + (size_t)(l & 15) * K + (l >> 4) * 8;
  f32x4 acc[4];
#pragma unroll
  for (int nt = 0; nt < 4; ++nt) acc[nt] = (f32x4){0.f, 0.f, 0.f, 0.f};
  for (int k0 = 0; k0 < K; k0 += 32) {
    short8 a = *(const short8*)(arow + k0);
#pragma unroll
    for (int nt = 0; nt < 4; ++nt) {
      short8 b = *(const short8*)(brow + (size_t)nt * 16 * K + k0);
      acc[nt] = __builtin_amdgcn_mfma_f32_16x16x32_bf16(a, b, acc[nt], 0, 0, 0);
    }
  }
#pragma unroll
  for (int nt = 0; nt < 4; ++nt)
#pragma unroll
    for (int q = 0; q < 4; ++q)
      C[(size_t)(m0 + w * 16 + (l >> 4) * 4 + q) * N + nt * 16 + (l & 15)] = acc[nt][q];
}

// bf16 copy of a mode-aware buffer (8 elems/thread). n8 = elems/8.
__global__ __launch_bounds__(256) void convert_bf16(const void* __restrict__ in,
    u16* __restrict__ out, int n8, const unsigned* __restrict__ modep) {
  int f32 = (int)*modep;
  int i = blockIdx.x * 256 + threadIdx.x;
  if (i >= n8) return;
  if (f32) {
    float4 v0 = ((const float4*)in)[(size_t)i * 2];
    float4 v1 = ((const float4*)in)[(size_t)i * 2 + 1];
    ushort4 o0 = {f2bf(v0.x), f2bf(v0.y), f2bf(v0.z), f2bf(v0.w)};
    ushort4 o1 = {f2bf(v1.x), f2bf(v1.y), f2bf(v1.z), f2bf(v1.w)};
    ((ushort4*)out)[(size_t)i * 2] = o0;
    ((ushort4*)out)[(size_t)i * 2 + 1] = o1;
  } else {
    ((int4*)out)[i] = ((const int4*)in)[i];   // already bf16: raw copy
  }
}

// transpose + bf16 convert: in fp32 [M][F] -> out bf16 [F][M]. grid (M/32, F/32).
__global__ __launch_bounds__(256) void transpose_bf16(const float* __restrict__ in,
    u16* __restrict__ out, int M, int F) {
  __shared__ float t[32][33];
  int m0 = blockIdx.x * 32, f0 = blockIdx.y * 32;
  int c = threadIdx.x & 31, r = threadIdx.x >> 5;   // r = 0..7
  for (int rr = r; rr < 32; rr += 8)
    t[rr][c] = in[(size_t)(m0 + rr) * F + f0 + c];
  __syncthreads();
  for (int rr = r; rr < 32; rr += 8)
    out[(size_t)(f0 + rr) * M + m0 + c] = f2bf(t[c][rr]);
}

// dual fp32->bf16 transpose (whmu/whlv -> whmuT/whlvT). grid (M/32, F/32, 2).
__global__ __launch_bounds__(256) void transpose_pair(const float* __restrict__ in0,
    const float* __restrict__ in1, u16* __restrict__ out0, u16* __restrict__ out1,
    int M, int F) {
  const float* in = blockIdx.z ? in1 : in0;
  u16* out = blockIdx.z ? out1 : out0;
  __shared__ float t[32][33];
  int m0 = blockIdx.x * 32, f0 = blockIdx.y * 32;
  int c = threadIdx.x & 31, r = threadIdx.x >> 5;
  for (int rr = r; rr < 32; rr += 8)
    t[rr][c] = in[(size_t)(m0 + rr) * F + f0 + c];
  __syncthreads();
  for (int rr = r; rr < 32; rr += 8)
    out[(size_t)(f0 + rr) * M + m0 + c] = f2bf(t[c][rr]);
}

// transpose + bf16 convert from a RAW (mode-aware) buffer. grid (M/32, F/32).
__global__ __launch_bounds__(256) void transpose_any(const void* __restrict__ in,
    u16* __restrict__ out, int M, int F, const unsigned* __restrict__ modep) {
  int f32 = (int)*modep;
  __shared__ u16 t[32][33];
  int m0 = blockIdx.x * 32, f0 = blockIdx.y * 32;
  int c = threadIdx.x & 31, r = threadIdx.x >> 5;
  for (int rr = r; rr < 32; rr += 8)
    t[rr][c] = f2bf(ldf(in, (size_t)(m0 + rr) * F + f0 + c, f32));
  __syncthreads();
  for (int rr = r; rr < 32; rr += 8)
    out[(size_t)(f0 + rr) * M + m0 + c] = t[c][rr];
}

// dual raw transpose (Wmu/Wlv -> WmuT/WlvT). grid (M/32, F/32, 2).
__global__ __launch_bounds__(256) void transpose_w2(const void* __restrict__ in0,
    const void* __restrict__ in1, u16* __restrict__ out0, u16* __restrict__ out1,
    int M, int F, const unsigned* __restrict__ modep) {
  int f32 = (int)*modep;
  const void* in = blockIdx.z ? in1 : in0;
  u16* out = blockIdx.z ? out1 : out0;
  __shared__ u16 t[32][33];
  int m0 = blockIdx.x * 32, f0 = blockIdx.y * 32;
  int c = threadIdx.x & 31, r = threadIdx.x >> 5;
  for (int rr = r; rr < 32; rr += 8)
    t[rr][c] = f2bf(ldf(in, (size_t)(m0 + rr) * F + f0 + c, f32));
  __syncthreads();
  for (int rr = r; rr < 32; rr += 8)
    out[(size_t)(f0 + rr) * M + m0 + c] = t[c][rr];
}

// s_i = Wh_i . a[:F], d_i = Wh_i . a[F:] (Wh fp32, a raw). NO atomics.
__global__ __launch_bounds__(256) void sd_f32(const float* __restrict__ Wh,
    const void* __restrict__ a2, float* __restrict__ s, float* __restrict__ d,
    int F, const unsigned* __restrict__ modep) {
  int f32 = (int)*modep;
  int row = blockIdx.x * 4 + (threadIdx.x >> 6);
  int l = threadIdx.x & 63;
  float ss = 0.f, dd = 0.f;
  for (int k = l; k < F; k += 64) {
    float wv = Wh[(size_t)row * F + k];
    ss += wv * ldf(a2, k, f32);
    dd += wv * ldf(a2, F + k, f32);
  }
#pragma unroll
  for (int off = 32; off > 0; off >>= 1) {
    ss += __shfl_down(ss, off, 64);
    dd += __shfl_down(dd, off, 64);
  }
  if (l == 0) { s[row] = ss; d[row] = dd; }
}

// dual s/d for layers 2/3 (F = 64). grid (2048, 2). NO atomics.
__global__ __launch_bounds__(256) void sd_dual(const float* __restrict__ Wh0,
    const float* __restrict__ Wh1, const void* __restrict__ a0,
    const void* __restrict__ a1, float* __restrict__ s0, float* __restrict__ s1,
    float* __restrict__ d0, float* __restrict__ d1,
    const unsigned* __restrict__ modep) {
  int f32 = (int)*modep;
  int L = blockIdx.y;
  const float* Wh = L ? Wh1 : Wh0;
  const void* a2 = L ? a1 : a0;
  int row = blockIdx.x * 4 + (threadIdx.x >> 6);
  int l = threadIdx.x & 63;
  float wv = Wh[(size_t)row * 64 + l];
  float ss = wv * ldf(a2, l, f32);
  float dd = wv * ldf(a2, 64 + l, f32);
#pragma unroll
  for (int off = 32; off > 0; off >>= 1) {
    ss += __shfl_down(ss, off, 64);
    dd += __shfl_down(dd, off, 64);
  }
  if (l == 0) { (L ? s1 : s0)[row] = ss; (L ? d1 : d0)[row] = dd; }
}

// Dmax: single block per array, LDS tree, plain store (no atomics, no
// contention). grid = #arrays; writes cells[blockIdx.x * 16] (64B apart).
__global__ __launch_bounds__(256) void dmax_reduce(const float* __restrict__ da,
    const float* __restrict__ db, float* __restrict__ cells) {
  const float* d = blockIdx.x ? db : da;
  __shared__ float red[256];
  float m = -3.4e38f;
  for (int i = threadIdx.x; i < NROW; i += 256) m = fmaxf(m, d[i]);
  red[threadIdx.x] = m;
  __syncthreads();
#pragma unroll
  for (int sft = 128; sft > 0; sft >>= 1) {
    if (threadIdx.x < sft) red[threadIdx.x] = fmaxf(red[threadIdx.x], red[threadIdx.x + sft]);
    __syncthreads();
  }
  if (threadIdx.x == 0) cells[blockIdx.x * 16] = red[0];
}

// swizzled P-fragment LDS byte offset:
// slot = L*8 + ks*2 + mh (1KB each); within: [row 0..15][kg 0..3] x 8 bf16,
// kg XOR'd with (row>>1)&3 to spread bank usage on b128 read/write.
__device__ __forceinline__ int pa_off(int L, int ks, int mh, int row, int kg) {
  return ((L * 8 + ks * 2 + mh) << 10) + (row << 6) + ((kg ^ ((row >> 1) & 3)) << 4);
}

// Flash GAT layer(s) on MFMA — JS=1: each block owns 32 output rows COMPLETELY.
// grid = 256 blocks x 512 threads (8 waves). ZERO global atomics: accumulator
// and lsum live entirely in-block; normalize + activation fused in epilogue.
// j-tile = 128 per iteration (NIT=64), ks=0..3 MFMA k-steps.
// Pipeline: raw s_barrier + lgkmcnt-only fence (global loads stay in flight),
// adjacency reg-prefetch depth 2, d_j staged once in LDS, PA double-buffered,
// setprio around the MFMA cluster.
// NL=1 (FDIM=256): waves 0-7 each own 2 n-tiles; epilogue -> elu -> bf16 hbf.
// NL=2 (FDIM=64): waves 0-3 layer a, 4-7 layer b, 1 n-tile each; epilogue
// -> div -> dual fp32 store (ws copy + d_out region).
template <int NL>
__global__ __launch_bounds__(512) void flash_mfma(
    const u16* __restrict__ whTa, const u16* __restrict__ whTb,   // bf16 [FDIM][NROW]
    const float* __restrict__ sa, const float* __restrict__ da,
    const float* __restrict__ sb, const float* __restrict__ db,
    const float* __restrict__ cella, const float* __restrict__ cellb,
    const void* __restrict__ adj, const unsigned* __restrict__ amodep,
    void* __restrict__ o0, void* __restrict__ o1,
    void* __restrict__ o2, void* __restrict__ o3) {
  constexpr int NIT = NROW / 128;            // 64 iterations
  constexpr int NTW = (NL == 1) ? 2 : 1;     // n-tiles per wave
  constexpr int FDIM = (NL == 1) ? 256 : 64;
  __shared__ __align__(16) char PA[2][NL * 8192];   // double-buffered P frags
  __shared__ __align__(16) float dd_[NL][NROW];     // full d_j (prologue stage)
  __shared__ float sv_[NL][32], Ms_[NL][32], ls_[NL][32];
  int tid = threadIdx.x;
  int amode = (int)*amodep;
  int r0 = blockIdx.x * 32;
  if (tid < 32 * NL) {
    int L = tid >> 5, i = tid & 31;
    float Dm = L ? *cellb : *cella;
    float t0 = (L ? sb : sa)[r0 + i];
    sv_[L][i] = t0;
    float m = t0 + Dm;
    Ms_[L][i] = fmaxf(m, 0.2f * m);   // lrelu(s_i + Dmax) >= all e[i,:]
  }
  // stage the full d_j array (float4 coalesced)
  for (int u = tid; u < NL * (NROW / 4); u += 512) {
    int L = u / (NROW / 4), uu = u - L * (NROW / 4);
    ((float4*)dd_[L])[uu] = ((const float4*)(L ? db : da))[uu];
  }
  __syncthreads();
  // score-phase mapping: 32 rows x 16 j-octets (one octet = 8 j)
  int sr = tid >> 4, sjo = tid & 15;
  int ks_w = sjo >> 2, kg_w = sjo & 3, mh_w = sr >> 4, row_w = sr & 15;
  // PV-phase mapping
  int l = tid & 63, w = tid >> 6;
  int layer = (NL == 1) ? 0 : (w >> 2);
  int ntb = (NL == 1) ? (w * 2) : (w & 3);
  const u16* whT = layer ? whTb : whTa;
  f32x4 acc[2][NTW];
#pragma unroll
  for (int m = 0; m < 2; ++m)
#pragma unroll
    for (int n = 0; n < NTW; ++n) acc[m][n] = (f32x4){0.f, 0.f, 0.f, 0.f};
  float psum[NL];
#pragma unroll
  for (int L = 0; L < NL; ++L) psum[L] = 0.f;
  size_t abase = (size_t)(r0 + sr) * NROW + sjo * 8;

  // adjacency prefetch: depth 2 (static rotation)
  AdjRaw adjA = adj_load(adj, abase, amode);
  AdjRaw adjB = adj_load(adj, abase + 128, amode);
  for (int it = 0; it < NIT; ++it) {
    int j0 = it * 128;
    int cur = it & 1;
    // B fragments for this tile (issued first; L2-latency hidden under score)
    short8 bfr[4][NTW];
#pragma unroll
    for (int ks = 0; ks < 4; ++ks) {
      size_t jcol = (size_t)(j0 + ks * 32 + (l >> 4) * 8);
#pragma unroll
      for (int nt = 0; nt < NTW; ++nt)
        bfr[ks][nt] =
            *(const short8*)&whT[(size_t)((ntb + nt) * 16 + (l & 15)) * NROW + jcol];
    }
    // prefetch adjacency two iterations ahead
    AdjRaw adjN = adjB;
    if (it + 2 < NIT) adjN = adj_load(adj, abase + (size_t)(it + 2) * 128, amode);
    int aa[8];
    adj_decode(adjA, amode, aa);            // age-2 data: already drained
    // ---- score phase: P[sr, j0+sjo*8 .. +7] in bf16 into PA[cur]
    char* pab = PA[cur];
#pragma unroll
    for (int L = 0; L < NL; ++L) {
      float sv = sv_[L][sr], Mr = Ms_[L][sr];
      float4 dv0 = *(const float4*)&dd_[L][j0 + sjo * 8];
      float4 dv1 = *(const float4*)&dd_[L][j0 + sjo * 8 + 4];
      float dvv[8] = {dv0.x, dv0.y, dv0.z, dv0.w, dv1.x, dv1.y, dv1.z, dv1.w};
      short8 pk;
      float ps = 0.f;
#pragma unroll
      for (int q = 0; q < 8; ++q) {
        float t = sv + dvv[q];
        float e = fmaxf(t, 0.2f * t) - Mr;           // <= 0
        float p = aa[q] ? __expf(e) : 0.f;
        ps += p;
        pk[q] = (short)f2bf(p);
      }
      psum[L] += ps;
      *(short8*)(pab + pa_off(L, ks_w, mh_w, row_w, kg_w)) = pk;
    }
    // LDS-only fence + raw barrier: global loads stay outstanding
    asm volatile("s_waitcnt lgkmcnt(0)" ::: "memory");
    __builtin_amdgcn_s_barrier();
    __builtin_amdgcn_sched_barrier(0);
    // ---- PV phase: acc += P * WhT^T (MFMA)
    __builtin_amdgcn_s_setprio(1);
#pragma unroll
    for (int ks = 0; ks < 4; ++ks) {
      short8 a0 = *(const short8*)(pab + pa_off(layer, ks, 0, l & 15, l >> 4));
      short8 a1 = *(const short8*)(pab + pa_off(layer, ks, 1, l & 15, l >> 4));
#pragma unroll
      for (int nt = 0; nt < NTW; ++nt) {
        acc[0][nt] = __builtin_amdgcn_mfma_f32_16x16x32_bf16(a0, bfr[ks][nt],
                                                             acc[0][nt], 0, 0, 0);
        acc[1][nt] = __builtin_amdgcn_mfma_f32_16x16x32_bf16(a1, bfr[ks][nt],
                                                             acc[1][nt], 0, 0, 0);
      }
    }
    __builtin_amdgcn_s_setprio(0);
    // no second barrier: next score writes PA[cur^1]; its previous readers
    // (PV at it-1) completed before this iteration's barrier.
    adjA = adjB; adjB = adjN;
  }
  // ---- lsum: per-thread psum -> LDS (reuse PA) -> per-row sum (no atomics)
  __syncthreads();                    // last PV reads of PA done
  float* red = (float*)PA;
#pragma unroll
  for (int L = 0; L < NL; ++L) red[L * 512 + tid] = psum[L];
  __syncthreads();
  if (tid < 32 * NL) {
    int L = tid >> 5, r = tid & 31;
    float t = 0.f;
#pragma unroll
    for (int q = 0; q < 16; ++q) t += red[L * 512 + r * 16 + q];
    ls_[L][r] = t;
  }
  __syncthreads();
  // ---- fused epilogue (C/D layout: col=lane&15, row=(lane>>4)*4+q)
  if constexpr (NL == 1) {
    u16* hb = (u16*)o0;               // bf16 h = elu(acc/lsum)
#pragma unroll
    for (int m = 0; m < 2; ++m)
#pragma unroll
      for (int nt = 0; nt < NTW; ++nt)
#pragma unroll
        for (int q = 0; q < 4; ++q) {
          int r = m * 16 + (l >> 4) * 4 + q;
          int c = (ntb + nt) * 16 + (l & 15);
          float x = acc[m][nt][q] / ls_[0][r];
          x = (x > 0.f) ? x : (__expf(x) - 1.f);
          hb[(size_t)(r0 + r) * FDIM + c] = f2bf(x);
        }
  } else {
    float* of = (float*)(layer ? o2 : o0);   // ws copy
    float* od = (float*)(layer ? o3 : o1);   // d_out region
#pragma unroll
    for (int m = 0; m < 2; ++m)
#pragma unroll
      for (int q = 0; q < 4; ++q) {
        int r = m * 16 + (l >> 4) * 4 + q;
        int c = ntb * 16 + (l & 15);
        float x = acc[m][0][q] / ls_[layer][r];
        size_t idx = (size_t)(r0 + r) * FDIM + c;
        of[idx] = x;
        od[idx] = x;
      }
  }
}

// logits = (mu + eps*exp(0.5*logvar)) @ Wc + bc (mu/lv fp32, rest raw). fp32 out.
__global__ __launch_bounds__(256) void logits_f32(const float* __restrict__ mu,
    const float* __restrict__ lv, const void* __restrict__ eps,
    const void* __restrict__ Wc, const void* __restrict__ bcv,
    float* __restrict__ outL, const unsigned* __restrict__ modep) {
  int f32 = (int)*modep;
  __shared__ float zs[64 * 64];
  __shared__ float wcs[64 * 16];
  int tid = threadIdx.x;
  for (int i = tid; i < 1024; i += 256) wcs[i] = ldf(Wc, i, f32);
  int rl = tid >> 2, cs = (tid & 3) * 16;
  int row = blockIdx.x * 64 + rl;
  size_t rb64 = (size_t)row * 64;
  for (int c = cs; c < cs + 16; ++c)
    zs[rl * 64 + c] = mu[rb64 + c] + ldf(eps, rb64 + c, f32) * __expf(0.5f * lv[rb64 + c]);
  __syncthreads();
  for (int it = tid; it < 1024; it += 256) {
    int r = it >> 4, oc = it & 15;
    float a = ldf(bcv, oc, f32);
    for (int c = 0; c < 64; ++c) a += zs[r * 64 + c] * wcs[c * 16 + oc];
    outL[(size_t)(blockIdx.x * 64 + r) * 16 + oc] = a;
  }
}

extern "C" void kernel_launch(void* const* d_in, const int* in_sizes, int n_in,
                              void* d_out, int out_size, void* d_ws, size_t ws_size,
                              hipStream_t stream) {
  (void)out_size; (void)ws_size;
  // ---- size-based input resolution (robust to permutation; ties in dict order)
  int ix = 0, iadj = 1, ieps = 2, iW1 = 3, ia1 = 4, iWmu = 5, iamu = 6,
      iWlv = 7, ialv = 8, iWc = 9, ibc = 10;
  {
    int fmu = -1, flv = -1, fam = -1, fal = -1;
    for (int i = 0; i < n_in; ++i) {
      switch (in_sizes[i]) {
        case 67108864: iadj = i; break;
        case 4194304:  ix   = i; break;
        case 524288:   ieps = i; break;
        case 131072:   iW1  = i; break;
        case 512:      ia1  = i; break;
        case 1024:     iWc  = i; break;
        case 16:       ibc  = i; break;
        case 16384:    if (fmu < 0) fmu = i; else flv = i; break;
        case 128:      if (fam < 0) fam = i; else fal = i; break;
        default: break;
      }
    }
    if (fmu >= 0 && flv >= 0) { iWmu = fmu; iWlv = flv; }
    if (fam >= 0 && fal >= 0) { iamu = fam; ialv = fal; }
  }
  const void* adj = d_in[iadj];
  char* ws = (char*)d_ws;
  const size_t KB = 1024, MB = 1024 * 1024;
  // ---- workspace (<= 24.6 MB) ----
  float* wh1   = (float*)(ws + 0);                 // 8MB [dead after sd1/transpose1]
  float* whmu  = (float*)(ws + 0);                 // 2MB [overlay]
  float* whlv  = (float*)(ws + 2 * MB);            // 2MB [overlay]
  float* muf   = (float*)(ws + 4 * MB);            // 2MB [overlay]
  float* lvf   = (float*)(ws + 6 * MB);            // 2MB [overlay]
  u16*   xbf   = (u16*)(ws + 8 * MB);              // 8MB bf16 x [dead after gemm1]
  u16*   whT1  = (u16*)(ws + 8 * MB);              // 4MB bf16 [256][8192] [overlay]
  u16*   hbf   = (u16*)(ws + 12 * MB);             // 4MB bf16 [8192][256]
  u16*   whmuT = (u16*)(ws + 20 * MB);             // 1MB bf16 [64][8192]
  u16*   whlvT = (u16*)(ws + 21 * MB);             // 1MB bf16 [64][8192]
  u16*   W1T   = (u16*)(ws + 22 * MB);             // 256KB bf16 [256][512]
  u16*   WmuT  = (u16*)(ws + 22 * MB + 256 * KB);  // 32KB bf16 [64][256]
  u16*   WlvT  = (u16*)(ws + 22 * MB + 288 * KB);  // 32KB bf16 [64][256]
  float* s1    = (float*)(ws + 24 * MB + 96 * KB);
  float* d1    = (float*)(ws + 24 * MB + 128 * KB);
  float* smu   = (float*)(ws + 24 * MB + 160 * KB);
  float* dmu   = (float*)(ws + 24 * MB + 192 * KB);
  float* slv   = (float*)(ws + 24 * MB + 224 * KB);
  float* dlv   = (float*)(ws + 24 * MB + 256 * KB);
  float* dmaxv = (float*)(ws + 24 * MB + 288 * KB);  // 3 cells, 64B apart
  unsigned* mode  = (unsigned*)(ws + 24 * MB + 289 * KB);
  unsigned* amode = (unsigned*)(ws + 24 * MB + 290 * KB);

  // fp32 output layout: [logits 8192*16 | mu 8192*64 | logvar 8192*64]
  float* out_logits = (float*)d_out;
  float* out_mu     = (float*)d_out + 131072;
  float* out_lv     = (float*)d_out + 655360;

  detect3<<<1, 256, 0, stream>>>((const u16*)d_in[ix], mode);
  detect_adj<<<1, 256, 0, stream>>>((const unsigned*)adj, amode);

  // layer 1: xbf/W1T bf16, Wh1 = xbf @ W1T^T (MFMA), WhT1 bf16, s/d + dmax,
  // JS=1 flash (256 blocks x 512 thr, zero atomics, fused elu->hbf)
  convert_bf16<<<2048, 256, 0, stream>>>(d_in[ix], xbf, 524288, mode);
  transpose_any<<<dim3(16, 8), 256, 0, stream>>>(d_in[iW1], W1T, 512, 256, mode);
  gemm_mfma<<<dim3(4, 128), 256, 0, stream>>>(xbf, W1T, wh1, 512, 256);
  transpose_bf16<<<dim3(256, 8), 256, 0, stream>>>(wh1, whT1, 8192, 256);
  sd_f32<<<2048, 256, 0, stream>>>(wh1, d_in[ia1], s1, d1, 256, mode);
  dmax_reduce<<<1, 256, 0, stream>>>(d1, d1, dmaxv + 0);
  flash_mfma<1><<<256, 512, 0, stream>>>(whT1, nullptr, s1, d1,
      nullptr, nullptr, dmaxv + 0, nullptr, adj, amode,
      hbf, nullptr, nullptr, nullptr);

  // layers 2/3: dual MFMA GEMM from hbf, dual transposes, dual s/d + dmax,
  // FUSED JS=1 flash (zero atomics, fused div + dual store)
  transpose_w2<<<dim3(8, 2, 2), 256, 0, stream>>>(d_in[iWmu], d_in[iWlv],
      WmuT, WlvT, 256, 64, mode);
  gemm2_dual<<<dim3(2, 128), 256, 0, stream>>>(hbf, WmuT, WlvT, whmu, whlv);
  transpose_pair<<<dim3(256, 2, 2), 256, 0, stream>>>(whmu, whlv, whmuT, whlvT,
      8192, 64);
  sd_dual<<<dim3(2048, 2), 256, 0, stream>>>(whmu, whlv, d_in[iamu], d_in[ialv],
      smu, slv, dmu, dlv, mode);
  dmax_reduce<<<2, 256, 0, stream>>>(dmu, dlv, dmaxv + 16);
  flash_mfma<2><<<256, 512, 0, stream>>>(whmuT, whlvT, smu, dmu, slv, dlv,
      dmaxv + 16, dmaxv + 32, adj, amode,
      muf, out_mu, lvf, out_lv);

  logits_f32<<<128, 256, 0, stream>>>(muf, lvf, d_in[ieps], d_in[iWc], d_in[ibc], out_logits, mode);
}